// Round 7
// baseline (365.649 us; speedup 1.0000x reference)
//
#include <hip/hip_runtime.h>
#include <hip/hip_bf16.h>

typedef unsigned short u16;
typedef __attribute__((ext_vector_type(8))) short bf16x8;   // 8 bf16 = 4 VGPRs (MFMA A/B frag)
typedef __attribute__((ext_vector_type(4))) float f32x4;    // MFMA C/D frag
typedef __attribute__((ext_vector_type(4))) unsigned u32x4;

#define L2E 1.4426950408889634f

__device__ __forceinline__ u16 f2bf(float f) {
  unsigned u = __float_as_uint(f);
  u = u + 0x7fffu + ((u >> 16) & 1u);   // RNE
  return (u16)(u >> 16);
}
__device__ __forceinline__ float bf2f(short s) {
  return __uint_as_float(((unsigned)(u16)s) << 16);
}
__device__ __forceinline__ unsigned pkbf(float a, float b) {   // low = a, high = b (RNE)
  return ((unsigned)f2bf(b) << 16) | f2bf(a);
}
__device__ __forceinline__ float lo16(unsigned v) { return __uint_as_float(v << 16); }
__device__ __forceinline__ float hi16(unsigned v) { return __uint_as_float(v & 0xffff0000u); }

// ---------------- prep: f32 -> bf16 elementwise ----------------
__global__ void conv_f32_bf16(const float* __restrict__ in, u16* __restrict__ out, int n4) {
  int i = blockIdx.x * blockDim.x + threadIdx.x;
  int stride = gridDim.x * blockDim.x;
  for (; i < n4; i += stride) {
    float4 v = ((const float4*)in)[i];
    ushort4 o = make_ushort4(f2bf(v.x), f2bf(v.y), f2bf(v.z), f2bf(v.w));
    ((ushort4*)out)[i] = o;
  }
}

// ---------------- prep: W[k][n] f32 -> Wt[n][k] bf16 ----------------
__global__ void wtrans(const float* __restrict__ W, u16* __restrict__ Wt) {
  __shared__ float T[32][33];
  int k0 = blockIdx.y * 32, n0 = blockIdx.x * 32;
  int tx = threadIdx.x, ty = threadIdx.y;       // (32,8)
  #pragma unroll
  for (int j = 0; j < 4; ++j) T[ty + 8*j][tx] = W[(size_t)(k0 + ty + 8*j) * 1024 + n0 + tx];
  __syncthreads();
  #pragma unroll
  for (int j = 0; j < 4; ++j) Wt[(size_t)(n0 + ty + 8*j) * 1024 + k0 + tx] = f2bf(T[tx][ty + 8*j]);
}

// ---------------- QKV projection GEMM (3 fused via blockIdx.z), global_load_lds staging ----------------
// z==2 (V projection) writes V^T [B,H,64,S] directly -> vtrans kernel deleted.
__global__ __launch_bounds__(256) void qkv_gemm3(const u16* __restrict__ X1, const u16* __restrict__ X2,
                                                 const u16* __restrict__ Wtq, const u16* __restrict__ Wtk,
                                                 const u16* __restrict__ Wtv,
                                                 const float* __restrict__ bq, const float* __restrict__ bk,
                                                 const float* __restrict__ bv,
                                                 u16* __restrict__ Qo, u16* __restrict__ Ko, u16* __restrict__ Vo) {
  int z = blockIdx.z;
  const u16* X   = (z == 0) ? X1 : X2;
  const u16* Wt  = (z == 0) ? Wtq : (z == 1) ? Wtk : Wtv;
  const float* bias = (z == 0) ? bq : (z == 1) ? bk : bv;
  u16* outp = (z == 0) ? Qo : (z == 1) ? Ko : Vo;

  __shared__ __align__(16) u16 As[128 * 32];
  __shared__ __align__(16) u16 Bs[128 * 32];
  int tid = threadIdx.x;
  int m0 = blockIdx.y * 128, n0 = blockIdx.x * 128;
  int w = tid >> 6, l = tid & 63;
  int wm = w >> 1, wn = w & 1;
  const int4* Xs = (const int4*)X;
  const int4* Ws = (const int4*)Wt;
  int4* As4 = (int4*)As;
  int4* Bs4 = (int4*)Bs;
  f32x4 acc[4][4] = {};
  for (int kt = 0; kt < 32; ++kt) {
    #pragma unroll
    for (int c = 0; c < 2; ++c) {
      int i = c * 256 + tid;              // 0..511 int4 chunks; dest = wave-uniform base + lane*16
      int row = i >> 2, kc = i & 3;
      __builtin_amdgcn_global_load_lds(
          (const __attribute__((address_space(1))) void*)&Xs[(size_t)(m0 + row) * 128 + kt * 4 + kc],
          (__attribute__((address_space(3))) void*)&As4[i], 16, 0, 0);
      __builtin_amdgcn_global_load_lds(
          (const __attribute__((address_space(1))) void*)&Ws[(size_t)(n0 + row) * 128 + kt * 4 + kc],
          (__attribute__((address_space(3))) void*)&Bs4[i], 16, 0, 0);
    }
    __syncthreads();
    bf16x8 a[4], bb[4];
    #pragma unroll
    for (int mc = 0; mc < 4; ++mc) a[mc]  = *(const bf16x8*)&As[(wm*64 + mc*16 + (l & 15)) * 32 + (l >> 4) * 8];
    #pragma unroll
    for (int nc = 0; nc < 4; ++nc) bb[nc] = *(const bf16x8*)&Bs[(wn*64 + nc*16 + (l & 15)) * 32 + (l >> 4) * 8];
    #pragma unroll
    for (int mc = 0; mc < 4; ++mc)
      #pragma unroll
      for (int nc = 0; nc < 4; ++nc)
        acc[mc][nc] = __builtin_amdgcn_mfma_f32_16x16x32_bf16(a[mc], bb[nc], acc[mc][nc], 0, 0, 0);
    __syncthreads();
  }
  #pragma unroll
  for (int nc = 0; nc < 4; ++nc) {
    int n = n0 + wn * 64 + nc * 16 + (l & 15);
    float bvv = bias[n];
    int h = n >> 6, d = n & 63;
    #pragma unroll
    for (int mc = 0; mc < 4; ++mc) {
      int srow_base = m0 + wm * 64 + mc * 16 + (l >> 4) * 4;
      if (z == 2) {
        // V^T write: Vt[(b*16+h)*64 + d][s..s+3] — 4 consecutive u16 = one 8B store
        int b = srow_base >> 10, s = srow_base & 1023;   // srow_base % 4 == 0, no b-crossing in r
        ushort4 vv;
        vv.x = f2bf(acc[mc][nc][0] + bvv);
        vv.y = f2bf(acc[mc][nc][1] + bvv);
        vv.z = f2bf(acc[mc][nc][2] + bvv);
        vv.w = f2bf(acc[mc][nc][3] + bvv);
        *(ushort4*)&outp[((size_t)((b * 16 + h) * 64 + d)) * 1024 + s] = vv;
      } else {
        #pragma unroll
        for (int r = 0; r < 4; ++r) {
          int sm = srow_base + r;
          int b = sm >> 10, s = sm & 1023;
          outp[((size_t)((b * 16 + h) * 1024 + s)) * 64 + d] = f2bf(acc[mc][nc][r] + bvv);
        }
      }
    }
  }
}

// ---------------- fused double-softmax attention, v8 ----------------
// EXACT v6 structure (known-good swizzles/pipeline), with Vl ALIASED onto Kl:
// Kl live only in pass A, Vl only in pass B; lifetimes disjoint at barrier
// granularity (V tile0 staged into buf0 at pass-A t=7 after buf0's last read at
// t=6; V tile1 staged at pass-B t=0 into buf1 after its last read at t=7;
// redF (8.7KB) fits in KVl[0], dead after pass-B t=6 barrier).
// LDS 66.5KB -> ~33KB => 4 blocks/CU (16 waves/CU).
// grid 4096 = 8 xcd x 16 bh x 32 qt.
__global__ __launch_bounds__(256, 4) void attn8(const u16* __restrict__ Q, const u16* __restrict__ K,
                                                const u16* __restrict__ Vt, const float* __restrict__ mask,
                                                const int* __restrict__ clp, float* __restrict__ out) {
  __shared__ __align__(16) u16 KVl[2][8192];   // pass A: K tiles [128 keys][64 d]; pass B: V tiles [64 d][128 keys]
  __shared__ float m1p[2][2][16];
  __shared__ float z1p[2][2][16];
  __shared__ float z2p[2][2][16];

  int bid = blockIdx.x;
  int xcd = bid & 7, idx = bid >> 3;
  int bh = xcd * 16 + (idx >> 5);   // 32 q-tile blocks share (b,h) within an XCD
  int qt = idx & 31;
  int b = bh >> 4, h = bh & 15;
  int tid = threadIdx.x;
  int w = tid >> 6, l = tid & 63;
  int lq = l & 15, g = l >> 4;
  int qg = w >> 1, kh = w & 1;
  int qb = qt * 32 + qg * 16;

  const float* mrow = mask + b * 1024;
  const u16* Kb = K + (size_t)bh * 65536;
  const u16* Vb = Vt + (size_t)bh * 65536;
  int cl = clp[0];

  // K stage: dest chunk i=(row,ch of 8); src chunk = ch ^ F(row), F = (row&3)|(((row>>3 ^ row>>4)&1)<<2)
#define STAGE_K(bi, t) do {                                                                  \
    _Pragma("unroll")                                                                        \
    for (int c_ = 0; c_ < 4; ++c_) {                                                         \
      int i_ = c_ * 256 + tid; int row_ = i_ >> 3, ch_ = i_ & 7;                             \
      int f_ = (row_ & 3) | ((((row_ >> 3) ^ (row_ >> 4)) & 1) << 2);                        \
      __builtin_amdgcn_global_load_lds(                                                      \
        (const __attribute__((address_space(1))) void*)(Kb + (size_t)((t) * 128 + row_) * 64 + ((ch_ ^ f_) * 8)), \
        (__attribute__((address_space(3))) void*)&KVl[bi][i_ * 8], 16, 0, 0);                \
    } } while (0)

  // V stage (128-key tile): row=d (0..63, 16 chunks of 8 keys); src chunk = ch ^ (row&15)
#define STAGE_V(bi, t) do {                                                                  \
    _Pragma("unroll")                                                                        \
    for (int c_ = 0; c_ < 4; ++c_) {                                                         \
      int i_ = c_ * 256 + tid; int row_ = i_ >> 4, ch_ = i_ & 15;                            \
      __builtin_amdgcn_global_load_lds(                                                      \
        (const __attribute__((address_space(1))) void*)(Vb + (size_t)row_ * 1024 + (t) * 128 + ((ch_ ^ (row_ & 15)) * 8)), \
        (__attribute__((address_space(3))) void*)&KVl[bi][i_ * 8], 16, 0, 0);                \
    } } while (0)

  STAGE_K(0, 0);

  const u16* Qp = Q + ((size_t)bh * 1024 + qb + lq) * 64 + g * 8;
  bf16x8 qf0 = *(const bf16x8*)Qp;
  bf16x8 qf1 = *(const bf16x8*)(Qp + 32);

  __syncthreads();   // K0 staged

  // ---- pass A: swapped QK^T over 8 K-tiles (wave's kh-half of each) ----
  const float sl2e = 0.125f * L2E;
  unsigned sp[64];
  float rmax = -1e30f;
  int cur = 0;
  #pragma unroll
  for (int t = 0; t < 8; ++t) {
    if (t < 7) STAGE_K(cur ^ 1, t + 1);
    else       STAGE_V(0, 0);
    #pragma unroll
    for (int ct = 0; ct < 4; ++ct) {
      int m = ct >> 1, c = ct & 1;
      int row128 = kh * 64 + m * 32 + ((lq >> 2) << 3) + c * 4 + (lq & 3);   // kappa
      int F = (row128 & 3) | ((((row128 >> 3) ^ (row128 >> 4)) & 1) << 2);
      bf16x8 kf0 = *(const bf16x8*)&KVl[cur][row128 * 64 + ((g ^ F) * 8)];
      bf16x8 kf1 = *(const bf16x8*)&KVl[cur][row128 * 64 + (((g + 4) ^ F) * 8)];
      f32x4 tt = {0.f, 0.f, 0.f, 0.f};
      tt = __builtin_amdgcn_mfma_f32_16x16x32_bf16(kf0, qf0, tt, 0, 0, 0);
      tt = __builtin_amdgcn_mfma_f32_16x16x32_bf16(kf1, qf1, tt, 0, 0, 0);
      // lane (g,lq): C slot sigma = ct*16 + g*4 + r -> key t*128 + kh*64 + m*32 + g*8 + c*4 + r
      float4 mk = *(const float4*)(mrow + t * 128 + kh * 64 + m * 32 + g * 8 + c * 4);
      float s0 = fmaf(tt[0], sl2e, mk.x * L2E);
      float s1 = fmaf(tt[1], sl2e, mk.y * L2E);
      float s2 = fmaf(tt[2], sl2e, mk.z * L2E);
      float s3 = fmaf(tt[3], sl2e, mk.w * L2E);
      rmax = fmaxf(rmax, fmaxf(fmaxf(s0, s1), fmaxf(s2, s3)));
      sp[t * 8 + m * 4 + c * 2 + 0] = pkbf(s0, s1);
      sp[t * 8 + m * 4 + c * 2 + 1] = pkbf(s2, s3);
    }
    __syncthreads();
    cur ^= 1;
  }

  // ---- softmax-1: cross-kh m1, E = exp2(s-m1), cross-kh Z1 ----
  rmax = fmaxf(rmax, __shfl_xor(rmax, 16));
  rmax = fmaxf(rmax, __shfl_xor(rmax, 32));
  if (l < 16) m1p[kh][qg][l] = rmax;
  __syncthreads();
  float m1 = fmaxf(m1p[0][qg][lq], m1p[1][qg][lq]);
  float z1 = 0.f;
  #pragma unroll
  for (int i = 0; i < 64; ++i) {
    unsigned v = sp[i];
    float e0 = __builtin_amdgcn_exp2f(lo16(v) - m1);
    float e1 = __builtin_amdgcn_exp2f(hi16(v) - m1);
    z1 += e0 + e1;
    sp[i] = pkbf(e0, e1);
  }
  z1 += __shfl_xor(z1, 16);
  z1 += __shfl_xor(z1, 32);
  if (l < 16) z1p[kh][qg][l] = z1;
  __syncthreads();
  float Z1 = z1p[0][qg][lq] + z1p[1][qg][lq];
  float iz1 = __builtin_amdgcn_rcpf(Z1);
  float cr = L2E * iz1;

  // ---- pass B: p2 = exp2(mask*L2E - cr*E), PV over 8 V-tiles (wave's kh-half) ----
  f32x4 acc[4] = {};
  float z2 = 0.f;
  #pragma unroll
  for (int t = 0; t < 8; ++t) {
    if (t < 7) STAGE_V((t + 1) & 1, t + 1);
    #pragma unroll
    for (int mm = 0; mm < 2; ++mm) {
      int kb = t * 128 + kh * 64 + mm * 32;     // global key base of this 32-chunk
      bf16x8 pf;
      if (cl) {
        float4 mk0 = *(const float4*)(mrow + kb + g * 8);
        float4 mk1 = *(const float4*)(mrow + kb + g * 8 + 4);
        unsigned e01 = sp[t * 8 + mm * 4 + 0], e23 = sp[t * 8 + mm * 4 + 1];
        unsigned e45 = sp[t * 8 + mm * 4 + 2], e67 = sp[t * 8 + mm * 4 + 3];
        float p0 = __builtin_amdgcn_exp2f(fmaf(mk0.x, L2E, -cr * lo16(e01)));
        float p1 = __builtin_amdgcn_exp2f(fmaf(mk0.y, L2E, -cr * hi16(e01)));
        float p2 = __builtin_amdgcn_exp2f(fmaf(mk0.z, L2E, -cr * lo16(e23)));
        float p3 = __builtin_amdgcn_exp2f(fmaf(mk0.w, L2E, -cr * hi16(e23)));
        float p4 = __builtin_amdgcn_exp2f(fmaf(mk1.x, L2E, -cr * lo16(e45)));
        float p5 = __builtin_amdgcn_exp2f(fmaf(mk1.y, L2E, -cr * hi16(e45)));
        float p6 = __builtin_amdgcn_exp2f(fmaf(mk1.z, L2E, -cr * lo16(e67)));
        float p7 = __builtin_amdgcn_exp2f(fmaf(mk1.w, L2E, -cr * hi16(e67)));
        z2 += ((p0 + p1) + (p2 + p3)) + ((p4 + p5) + (p6 + p7));
        u32x4 pk = {pkbf(p0, p1), pkbf(p2, p3), pkbf(p4, p5), pkbf(p6, p7)};
        pf = __builtin_bit_cast(bf16x8, pk);
      } else {
        u32x4 pk = {sp[t * 8 + mm * 4 + 0], sp[t * 8 + mm * 4 + 1],
                    sp[t * 8 + mm * 4 + 2], sp[t * 8 + mm * 4 + 3]};
        pf = __builtin_bit_cast(bf16x8, pk);
      }
      #pragma unroll
      for (int dc = 0; dc < 4; ++dc) {
        int row = dc * 16 + lq;
        int ch = (kh * 8 + mm * 4 + g) ^ (row & 15);
        bf16x8 vf = *(const bf16x8*)&KVl[t & 1][row * 128 + ch * 8];
        acc[dc] = __builtin_amdgcn_mfma_f32_16x16x32_bf16(pf, vf, acc[dc], 0, 0, 0);
      }
    }
    if (t < 7) __syncthreads();
  }

  // ---- epilogue: cross-kh reduce acc (overlay dead KVl[0]) + scale ----
  z2 += __shfl_xor(z2, 16);
  z2 += __shfl_xor(z2, 32);
  if (l < 16) z2p[kh][qg][l] = z2;
  float* redF = (float*)&KVl[0][0];    // [2 qg][16 q][68 d-stride] = 8.7KB, inside KVl[0] (16KB)
  if (kh == 1) {
    #pragma unroll
    for (int dc = 0; dc < 4; ++dc)
      #pragma unroll
      for (int r = 0; r < 4; ++r)
        redF[qg * 1088 + (g * 4 + r) * 68 + dc * 16 + lq] = acc[dc][r];
  }
  __syncthreads();
  if (kh == 0) {
    float Z2 = z2p[0][qg][lq] + z2p[1][qg][lq];
    float phi = cl ? __builtin_amdgcn_rcpf(Z2) : iz1;   // value for q-row lq
    #pragma unroll
    for (int r = 0; r < 4; ++r) {
      float ph = __shfl(phi, g * 4 + r);
      size_t orow = ((size_t)(b * 1024 + qb + g * 4 + r)) * 1024 + h * 64;
      #pragma unroll
      for (int dc = 0; dc < 4; ++dc) {
        float o = acc[dc][r] + redF[qg * 1088 + (g * 4 + r) * 68 + dc * 16 + lq];
        out[orow + dc * 16 + lq] = o * ph;
      }
    }
  }
#undef STAGE_K
#undef STAGE_V
}

extern "C" void kernel_launch(void* const* d_in, const int* in_sizes, int n_in,
                              void* d_out, int out_size, void* d_ws, size_t ws_size,
                              hipStream_t stream) {
  const float* s1   = (const float*)d_in[0];
  const float* s2   = (const float*)d_in[1];
  const float* mask = (const float*)d_in[2];
  const float* Wq   = (const float*)d_in[3];
  const float* bq   = (const float*)d_in[4];
  const float* Wk   = (const float*)d_in[5];
  const float* bk   = (const float*)d_in[6];
  const float* Wv   = (const float*)d_in[7];
  const float* bv   = (const float*)d_in[8];
  const int*   cl   = (const int*)d_in[9];
  float* out = (float*)d_out;

  // ws layout (u16 elements): X1[8M] X2[8M] Wtq[1M] Wtk[1M] Wtv[1M] Q[8M] K[8M] Vt[8M]
  u16* ws  = (u16*)d_ws;
  const size_t M1 = 1024 * 1024;
  u16* X1  = ws;
  u16* X2  = ws + 8 * M1;
  u16* Wtq = ws + 16 * M1;
  u16* Wtk = Wtq + M1;
  u16* Wtv = Wtk + M1;
  u16* Qb  = Wtv + M1;
  u16* Kb  = Qb + 8 * M1;
  u16* Vtb = Kb + 8 * M1;   // V^T written directly by qkv_gemm3 (z==2)

  conv_f32_bf16<<<2048, 256, 0, stream>>>(s1, X1, 2097152);
  conv_f32_bf16<<<2048, 256, 0, stream>>>(s2, X2, 2097152);
  dim3 wtb(32, 8);
  wtrans<<<dim3(32, 32), wtb, 0, stream>>>(Wq, Wtq);
  wtrans<<<dim3(32, 32), wtb, 0, stream>>>(Wk, Wtk);
  wtrans<<<dim3(32, 32), wtb, 0, stream>>>(Wv, Wtv);
  qkv_gemm3<<<dim3(8, 64, 3), 256, 0, stream>>>(X1, X2, Wtq, Wtk, Wtv, bq, bk, bv, Qb, Kb, Vtb);
  attn8<<<4096, 256, 0, stream>>>(Qb, Kb, Vtb, mask, cl, out);
}

// Round 8
// 270.350 us; speedup vs baseline: 1.3525x; 1.3525x over previous
//
#include <hip/hip_runtime.h>
#include <hip/hip_bf16.h>

typedef unsigned short u16;
typedef __attribute__((ext_vector_type(8))) short bf16x8;   // 8 bf16 = 4 VGPRs (MFMA A/B frag)
typedef __attribute__((ext_vector_type(4))) float f32x4;    // MFMA C/D frag
typedef __attribute__((ext_vector_type(4))) unsigned u32x4;

#define L2E 1.4426950408889634f

__device__ __forceinline__ u16 f2bf(float f) {
  unsigned u = __float_as_uint(f);
  u = u + 0x7fffu + ((u >> 16) & 1u);   // RNE
  return (u16)(u >> 16);
}
__device__ __forceinline__ float bf2f(short s) {
  return __uint_as_float(((unsigned)(u16)s) << 16);
}
__device__ __forceinline__ unsigned pkbf(float a, float b) {   // low = a, high = b (RNE)
  return ((unsigned)f2bf(b) << 16) | f2bf(a);
}
__device__ __forceinline__ float lo16(unsigned v) { return __uint_as_float(v << 16); }
__device__ __forceinline__ float hi16(unsigned v) { return __uint_as_float(v & 0xffff0000u); }

// ---------------- prep: f32 -> bf16 elementwise ----------------
__global__ void conv_f32_bf16(const float* __restrict__ in, u16* __restrict__ out, int n4) {
  int i = blockIdx.x * blockDim.x + threadIdx.x;
  int stride = gridDim.x * blockDim.x;
  for (; i < n4; i += stride) {
    float4 v = ((const float4*)in)[i];
    ushort4 o = make_ushort4(f2bf(v.x), f2bf(v.y), f2bf(v.z), f2bf(v.w));
    ((ushort4*)out)[i] = o;
  }
}

// ---------------- prep: W[k][n] f32 -> Wt[n][k] bf16 ----------------
__global__ void wtrans(const float* __restrict__ W, u16* __restrict__ Wt) {
  __shared__ float T[32][33];
  int k0 = blockIdx.y * 32, n0 = blockIdx.x * 32;
  int tx = threadIdx.x, ty = threadIdx.y;       // (32,8)
  #pragma unroll
  for (int j = 0; j < 4; ++j) T[ty + 8*j][tx] = W[(size_t)(k0 + ty + 8*j) * 1024 + n0 + tx];
  __syncthreads();
  #pragma unroll
  for (int j = 0; j < 4; ++j) Wt[(size_t)(n0 + ty + 8*j) * 1024 + k0 + tx] = f2bf(T[tx][ty + 8*j]);
}

// ---------------- QKV projection GEMM (3 fused via blockIdx.z), global_load_lds staging ----------------
// z==2 (V projection) writes V^T [B,H,64,S] directly -> vtrans kernel deleted.
__global__ __launch_bounds__(256) void qkv_gemm3(const u16* __restrict__ X1, const u16* __restrict__ X2,
                                                 const u16* __restrict__ Wtq, const u16* __restrict__ Wtk,
                                                 const u16* __restrict__ Wtv,
                                                 const float* __restrict__ bq, const float* __restrict__ bk,
                                                 const float* __restrict__ bv,
                                                 u16* __restrict__ Qo, u16* __restrict__ Ko, u16* __restrict__ Vo) {
  int z = blockIdx.z;
  const u16* X   = (z == 0) ? X1 : X2;
  const u16* Wt  = (z == 0) ? Wtq : (z == 1) ? Wtk : Wtv;
  const float* bias = (z == 0) ? bq : (z == 1) ? bk : bv;
  u16* outp = (z == 0) ? Qo : (z == 1) ? Ko : Vo;

  __shared__ __align__(16) u16 As[128 * 32];
  __shared__ __align__(16) u16 Bs[128 * 32];
  int tid = threadIdx.x;
  int m0 = blockIdx.y * 128, n0 = blockIdx.x * 128;
  int w = tid >> 6, l = tid & 63;
  int wm = w >> 1, wn = w & 1;
  const int4* Xs = (const int4*)X;
  const int4* Ws = (const int4*)Wt;
  int4* As4 = (int4*)As;
  int4* Bs4 = (int4*)Bs;
  f32x4 acc[4][4] = {};
  for (int kt = 0; kt < 32; ++kt) {
    #pragma unroll
    for (int c = 0; c < 2; ++c) {
      int i = c * 256 + tid;              // 0..511 int4 chunks; dest = wave-uniform base + lane*16
      int row = i >> 2, kc = i & 3;
      __builtin_amdgcn_global_load_lds(
          (const __attribute__((address_space(1))) void*)&Xs[(size_t)(m0 + row) * 128 + kt * 4 + kc],
          (__attribute__((address_space(3))) void*)&As4[i], 16, 0, 0);
      __builtin_amdgcn_global_load_lds(
          (const __attribute__((address_space(1))) void*)&Ws[(size_t)(n0 + row) * 128 + kt * 4 + kc],
          (__attribute__((address_space(3))) void*)&Bs4[i], 16, 0, 0);
    }
    __syncthreads();
    bf16x8 a[4], bb[4];
    #pragma unroll
    for (int mc = 0; mc < 4; ++mc) a[mc]  = *(const bf16x8*)&As[(wm*64 + mc*16 + (l & 15)) * 32 + (l >> 4) * 8];
    #pragma unroll
    for (int nc = 0; nc < 4; ++nc) bb[nc] = *(const bf16x8*)&Bs[(wn*64 + nc*16 + (l & 15)) * 32 + (l >> 4) * 8];
    #pragma unroll
    for (int mc = 0; mc < 4; ++mc)
      #pragma unroll
      for (int nc = 0; nc < 4; ++nc)
        acc[mc][nc] = __builtin_amdgcn_mfma_f32_16x16x32_bf16(a[mc], bb[nc], acc[mc][nc], 0, 0, 0);
    __syncthreads();
  }
  #pragma unroll
  for (int nc = 0; nc < 4; ++nc) {
    int n = n0 + wn * 64 + nc * 16 + (l & 15);
    float bvv = bias[n];
    int h = n >> 6, d = n & 63;
    #pragma unroll
    for (int mc = 0; mc < 4; ++mc) {
      int srow_base = m0 + wm * 64 + mc * 16 + (l >> 4) * 4;
      if (z == 2) {
        // V^T write: Vt[(b*16+h)*64 + d][s..s+3] — 4 consecutive u16 = one 8B store
        int b = srow_base >> 10, s = srow_base & 1023;   // srow_base % 4 == 0, no b-crossing in r
        ushort4 vv;
        vv.x = f2bf(acc[mc][nc][0] + bvv);
        vv.y = f2bf(acc[mc][nc][1] + bvv);
        vv.z = f2bf(acc[mc][nc][2] + bvv);
        vv.w = f2bf(acc[mc][nc][3] + bvv);
        *(ushort4*)&outp[((size_t)((b * 16 + h) * 64 + d)) * 1024 + s] = vv;
      } else {
        #pragma unroll
        for (int r = 0; r < 4; ++r) {
          int sm = srow_base + r;
          int b = sm >> 10, s = sm & 1023;
          outp[((size_t)((b * 16 + h) * 1024 + s)) * 64 + d] = f2bf(acc[mc][nc][r] + bvv);
        }
      }
    }
  }
}

// ---------------- fused double-softmax attention, v9 ----------------
// v8 structure (Vl aliased onto Kl, ~33KB LDS) with v6's launch bounds (256,2):
// the min-waves bound is only a minimum — allocator returns to the natural
// ~108-VGPR codegen (no spill), and achieved occupancy floats to
// min(LDS: 160/33.8 = 4, VGPR: floor(512/108) = 4 waves/SIMD) = 4 blocks/CU.
// grid 4096 = 8 xcd x 16 bh x 32 qt.
__global__ __launch_bounds__(256, 2) void attn9(const u16* __restrict__ Q, const u16* __restrict__ K,
                                                const u16* __restrict__ Vt, const float* __restrict__ mask,
                                                const int* __restrict__ clp, float* __restrict__ out) {
  __shared__ __align__(16) u16 KVl[2][8192];   // pass A: K tiles [128 keys][64 d]; pass B: V tiles [64 d][128 keys]
  __shared__ float m1p[2][2][16];
  __shared__ float z1p[2][2][16];
  __shared__ float z2p[2][2][16];

  int bid = blockIdx.x;
  int xcd = bid & 7, idx = bid >> 3;
  int bh = xcd * 16 + (idx >> 5);   // 32 q-tile blocks share (b,h) within an XCD
  int qt = idx & 31;
  int b = bh >> 4, h = bh & 15;
  int tid = threadIdx.x;
  int w = tid >> 6, l = tid & 63;
  int lq = l & 15, g = l >> 4;
  int qg = w >> 1, kh = w & 1;
  int qb = qt * 32 + qg * 16;

  const float* mrow = mask + b * 1024;
  const u16* Kb = K + (size_t)bh * 65536;
  const u16* Vb = Vt + (size_t)bh * 65536;
  int cl = clp[0];

  // K stage: dest chunk i=(row,ch of 8); src chunk = ch ^ F(row), F = (row&3)|(((row>>3 ^ row>>4)&1)<<2)
#define STAGE_K(bi, t) do {                                                                  \
    _Pragma("unroll")                                                                        \
    for (int c_ = 0; c_ < 4; ++c_) {                                                         \
      int i_ = c_ * 256 + tid; int row_ = i_ >> 3, ch_ = i_ & 7;                             \
      int f_ = (row_ & 3) | ((((row_ >> 3) ^ (row_ >> 4)) & 1) << 2);                        \
      __builtin_amdgcn_global_load_lds(                                                      \
        (const __attribute__((address_space(1))) void*)(Kb + (size_t)((t) * 128 + row_) * 64 + ((ch_ ^ f_) * 8)), \
        (__attribute__((address_space(3))) void*)&KVl[bi][i_ * 8], 16, 0, 0);                \
    } } while (0)

  // V stage (128-key tile): row=d (0..63, 16 chunks of 8 keys); src chunk = ch ^ (row&15)
#define STAGE_V(bi, t) do {                                                                  \
    _Pragma("unroll")                                                                        \
    for (int c_ = 0; c_ < 4; ++c_) {                                                         \
      int i_ = c_ * 256 + tid; int row_ = i_ >> 4, ch_ = i_ & 15;                            \
      __builtin_amdgcn_global_load_lds(                                                      \
        (const __attribute__((address_space(1))) void*)(Vb + (size_t)row_ * 1024 + (t) * 128 + ((ch_ ^ (row_ & 15)) * 8)), \
        (__attribute__((address_space(3))) void*)&KVl[bi][i_ * 8], 16, 0, 0);                \
    } } while (0)

  STAGE_K(0, 0);

  const u16* Qp = Q + ((size_t)bh * 1024 + qb + lq) * 64 + g * 8;
  bf16x8 qf0 = *(const bf16x8*)Qp;
  bf16x8 qf1 = *(const bf16x8*)(Qp + 32);

  __syncthreads();   // K0 staged

  // ---- pass A: swapped QK^T over 8 K-tiles (wave's kh-half of each) ----
  const float sl2e = 0.125f * L2E;
  unsigned sp[64];
  float rmax = -1e30f;
  int cur = 0;
  #pragma unroll
  for (int t = 0; t < 8; ++t) {
    if (t < 7) STAGE_K(cur ^ 1, t + 1);
    else       STAGE_V(0, 0);
    #pragma unroll
    for (int ct = 0; ct < 4; ++ct) {
      int m = ct >> 1, c = ct & 1;
      int row128 = kh * 64 + m * 32 + ((lq >> 2) << 3) + c * 4 + (lq & 3);   // kappa
      int F = (row128 & 3) | ((((row128 >> 3) ^ (row128 >> 4)) & 1) << 2);
      bf16x8 kf0 = *(const bf16x8*)&KVl[cur][row128 * 64 + ((g ^ F) * 8)];
      bf16x8 kf1 = *(const bf16x8*)&KVl[cur][row128 * 64 + (((g + 4) ^ F) * 8)];
      f32x4 tt = {0.f, 0.f, 0.f, 0.f};
      tt = __builtin_amdgcn_mfma_f32_16x16x32_bf16(kf0, qf0, tt, 0, 0, 0);
      tt = __builtin_amdgcn_mfma_f32_16x16x32_bf16(kf1, qf1, tt, 0, 0, 0);
      // lane (g,lq): C slot sigma = ct*16 + g*4 + r -> key t*128 + kh*64 + m*32 + g*8 + c*4 + r
      float4 mk = *(const float4*)(mrow + t * 128 + kh * 64 + m * 32 + g * 8 + c * 4);
      float s0 = fmaf(tt[0], sl2e, mk.x * L2E);
      float s1 = fmaf(tt[1], sl2e, mk.y * L2E);
      float s2 = fmaf(tt[2], sl2e, mk.z * L2E);
      float s3 = fmaf(tt[3], sl2e, mk.w * L2E);
      rmax = fmaxf(rmax, fmaxf(fmaxf(s0, s1), fmaxf(s2, s3)));
      sp[t * 8 + m * 4 + c * 2 + 0] = pkbf(s0, s1);
      sp[t * 8 + m * 4 + c * 2 + 1] = pkbf(s2, s3);
    }
    __syncthreads();
    cur ^= 1;
  }

  // ---- softmax-1: cross-kh m1, E = exp2(s-m1), cross-kh Z1 ----
  rmax = fmaxf(rmax, __shfl_xor(rmax, 16));
  rmax = fmaxf(rmax, __shfl_xor(rmax, 32));
  if (l < 16) m1p[kh][qg][l] = rmax;
  __syncthreads();
  float m1 = fmaxf(m1p[0][qg][lq], m1p[1][qg][lq]);
  float z1 = 0.f;
  #pragma unroll
  for (int i = 0; i < 64; ++i) {
    unsigned v = sp[i];
    float e0 = __builtin_amdgcn_exp2f(lo16(v) - m1);
    float e1 = __builtin_amdgcn_exp2f(hi16(v) - m1);
    z1 += e0 + e1;
    sp[i] = pkbf(e0, e1);
  }
  z1 += __shfl_xor(z1, 16);
  z1 += __shfl_xor(z1, 32);
  if (l < 16) z1p[kh][qg][l] = z1;
  __syncthreads();
  float Z1 = z1p[0][qg][lq] + z1p[1][qg][lq];
  float iz1 = __builtin_amdgcn_rcpf(Z1);
  float cr = L2E * iz1;

  // ---- pass B: p2 = exp2(mask*L2E - cr*E), PV over 8 V-tiles (wave's kh-half) ----
  f32x4 acc[4] = {};
  float z2 = 0.f;
  #pragma unroll
  for (int t = 0; t < 8; ++t) {
    if (t < 7) STAGE_V((t + 1) & 1, t + 1);
    #pragma unroll
    for (int mm = 0; mm < 2; ++mm) {
      int kb = t * 128 + kh * 64 + mm * 32;     // global key base of this 32-chunk
      bf16x8 pf;
      if (cl) {
        float4 mk0 = *(const float4*)(mrow + kb + g * 8);
        float4 mk1 = *(const float4*)(mrow + kb + g * 8 + 4);
        unsigned e01 = sp[t * 8 + mm * 4 + 0], e23 = sp[t * 8 + mm * 4 + 1];
        unsigned e45 = sp[t * 8 + mm * 4 + 2], e67 = sp[t * 8 + mm * 4 + 3];
        float p0 = __builtin_amdgcn_exp2f(fmaf(mk0.x, L2E, -cr * lo16(e01)));
        float p1 = __builtin_amdgcn_exp2f(fmaf(mk0.y, L2E, -cr * hi16(e01)));
        float p2 = __builtin_amdgcn_exp2f(fmaf(mk0.z, L2E, -cr * lo16(e23)));
        float p3 = __builtin_amdgcn_exp2f(fmaf(mk0.w, L2E, -cr * hi16(e23)));
        float p4 = __builtin_amdgcn_exp2f(fmaf(mk1.x, L2E, -cr * lo16(e45)));
        float p5 = __builtin_amdgcn_exp2f(fmaf(mk1.y, L2E, -cr * hi16(e45)));
        float p6 = __builtin_amdgcn_exp2f(fmaf(mk1.z, L2E, -cr * lo16(e67)));
        float p7 = __builtin_amdgcn_exp2f(fmaf(mk1.w, L2E, -cr * hi16(e67)));
        z2 += ((p0 + p1) + (p2 + p3)) + ((p4 + p5) + (p6 + p7));
        u32x4 pk = {pkbf(p0, p1), pkbf(p2, p3), pkbf(p4, p5), pkbf(p6, p7)};
        pf = __builtin_bit_cast(bf16x8, pk);
      } else {
        u32x4 pk = {sp[t * 8 + mm * 4 + 0], sp[t * 8 + mm * 4 + 1],
                    sp[t * 8 + mm * 4 + 2], sp[t * 8 + mm * 4 + 3]};
        pf = __builtin_bit_cast(bf16x8, pk);
      }
      #pragma unroll
      for (int dc = 0; dc < 4; ++dc) {
        int row = dc * 16 + lq;
        int ch = (kh * 8 + mm * 4 + g) ^ (row & 15);
        bf16x8 vf = *(const bf16x8*)&KVl[t & 1][row * 128 + ch * 8];
        acc[dc] = __builtin_amdgcn_mfma_f32_16x16x32_bf16(pf, vf, acc[dc], 0, 0, 0);
      }
    }
    if (t < 7) __syncthreads();
  }

  // ---- epilogue: cross-kh reduce acc (overlay dead KVl[0]) + scale ----
  z2 += __shfl_xor(z2, 16);
  z2 += __shfl_xor(z2, 32);
  if (l < 16) z2p[kh][qg][l] = z2;
  float* redF = (float*)&KVl[0][0];    // [2 qg][16 q][68 d-stride] = 8.7KB, inside KVl[0] (16KB)
  if (kh == 1) {
    #pragma unroll
    for (int dc = 0; dc < 4; ++dc)
      #pragma unroll
      for (int r = 0; r < 4; ++r)
        redF[qg * 1088 + (g * 4 + r) * 68 + dc * 16 + lq] = acc[dc][r];
  }
  __syncthreads();
  if (kh == 0) {
    float Z2 = z2p[0][qg][lq] + z2p[1][qg][lq];
    float phi = cl ? __builtin_amdgcn_rcpf(Z2) : iz1;   // value for q-row lq
    #pragma unroll
    for (int r = 0; r < 4; ++r) {
      float ph = __shfl(phi, g * 4 + r);
      size_t orow = ((size_t)(b * 1024 + qb + g * 4 + r)) * 1024 + h * 64;
      #pragma unroll
      for (int dc = 0; dc < 4; ++dc) {
        float o = acc[dc][r] + redF[qg * 1088 + (g * 4 + r) * 68 + dc * 16 + lq];
        out[orow + dc * 16 + lq] = o * ph;
      }
    }
  }
#undef STAGE_K
#undef STAGE_V
}

extern "C" void kernel_launch(void* const* d_in, const int* in_sizes, int n_in,
                              void* d_out, int out_size, void* d_ws, size_t ws_size,
                              hipStream_t stream) {
  const float* s1   = (const float*)d_in[0];
  const float* s2   = (const float*)d_in[1];
  const float* mask = (const float*)d_in[2];
  const float* Wq   = (const float*)d_in[3];
  const float* bq   = (const float*)d_in[4];
  const float* Wk   = (const float*)d_in[5];
  const float* bk   = (const float*)d_in[6];
  const float* Wv   = (const float*)d_in[7];
  const float* bv   = (const float*)d_in[8];
  const int*   cl   = (const int*)d_in[9];
  float* out = (float*)d_out;

  // ws layout (u16 elements): X1[8M] X2[8M] Wtq[1M] Wtk[1M] Wtv[1M] Q[8M] K[8M] Vt[8M]
  u16* ws  = (u16*)d_ws;
  const size_t M1 = 1024 * 1024;
  u16* X1  = ws;
  u16* X2  = ws + 8 * M1;
  u16* Wtq = ws + 16 * M1;
  u16* Wtk = Wtq + M1;
  u16* Wtv = Wtk + M1;
  u16* Qb  = Wtv + M1;
  u16* Kb  = Qb + 8 * M1;
  u16* Vtb = Kb + 8 * M1;   // V^T written directly by qkv_gemm3 (z==2)

  conv_f32_bf16<<<2048, 256, 0, stream>>>(s1, X1, 2097152);
  conv_f32_bf16<<<2048, 256, 0, stream>>>(s2, X2, 2097152);
  dim3 wtb(32, 8);
  wtrans<<<dim3(32, 32), wtb, 0, stream>>>(Wq, Wtq);
  wtrans<<<dim3(32, 32), wtb, 0, stream>>>(Wk, Wtk);
  wtrans<<<dim3(32, 32), wtb, 0, stream>>>(Wv, Wtv);
  qkv_gemm3<<<dim3(8, 64, 3), 256, 0, stream>>>(X1, X2, Wtq, Wtk, Wtv, bq, bk, bv, Qb, Kb, Vtb);
  attn9<<<4096, 256, 0, stream>>>(Qb, Kb, Vtb, mask, cl, out);
}

// Round 9
// 249.813 us; speedup vs baseline: 1.4637x; 1.0822x over previous
//
#include <hip/hip_runtime.h>
#include <hip/hip_bf16.h>

typedef unsigned short u16;
typedef __attribute__((ext_vector_type(8))) short bf16x8;   // 8 bf16 = 4 VGPRs (MFMA A/B frag)
typedef __attribute__((ext_vector_type(4))) float f32x4;    // MFMA C/D frag
typedef __attribute__((ext_vector_type(4))) unsigned u32x4;

#define L2E 1.4426950408889634f

__device__ __forceinline__ u16 f2bf(float f) {
  unsigned u = __float_as_uint(f);
  u = u + 0x7fffu + ((u >> 16) & 1u);   // RNE
  return (u16)(u >> 16);
}
__device__ __forceinline__ unsigned pkbf(float a, float b) {   // low = a, high = b (RNE)
  return ((unsigned)f2bf(b) << 16) | f2bf(a);
}

// ---------------- prep: f32 -> bf16 elementwise ----------------
__global__ void conv_f32_bf16(const float* __restrict__ in, u16* __restrict__ out, int n4) {
  int i = blockIdx.x * blockDim.x + threadIdx.x;
  int stride = gridDim.x * blockDim.x;
  for (; i < n4; i += stride) {
    float4 v = ((const float4*)in)[i];
    ushort4 o = make_ushort4(f2bf(v.x), f2bf(v.y), f2bf(v.z), f2bf(v.w));
    ((ushort4*)out)[i] = o;
  }
}

// ---------------- prep: W[k][n] f32 -> Wt[n][k] bf16 ----------------
__global__ void wtrans(const float* __restrict__ W, u16* __restrict__ Wt) {
  __shared__ float T[32][33];
  int k0 = blockIdx.y * 32, n0 = blockIdx.x * 32;
  int tx = threadIdx.x, ty = threadIdx.y;       // (32,8)
  #pragma unroll
  for (int j = 0; j < 4; ++j) T[ty + 8*j][tx] = W[(size_t)(k0 + ty + 8*j) * 1024 + n0 + tx];
  __syncthreads();
  #pragma unroll
  for (int j = 0; j < 4; ++j) Wt[(size_t)(n0 + ty + 8*j) * 1024 + k0 + tx] = f2bf(T[tx][ty + 8*j]);
}

// ---------------- QKV projection GEMM (3 fused via blockIdx.z), global_load_lds staging ----------------
// z==2 (V projection) writes V^T [B,H,64,S] directly -> vtrans kernel deleted.
__global__ __launch_bounds__(256) void qkv_gemm3(const u16* __restrict__ X1, const u16* __restrict__ X2,
                                                 const u16* __restrict__ Wtq, const u16* __restrict__ Wtk,
                                                 const u16* __restrict__ Wtv,
                                                 const float* __restrict__ bq, const float* __restrict__ bk,
                                                 const float* __restrict__ bv,
                                                 u16* __restrict__ Qo, u16* __restrict__ Ko, u16* __restrict__ Vo) {
  int z = blockIdx.z;
  const u16* X   = (z == 0) ? X1 : X2;
  const u16* Wt  = (z == 0) ? Wtq : (z == 1) ? Wtk : Wtv;
  const float* bias = (z == 0) ? bq : (z == 1) ? bk : bv;
  u16* outp = (z == 0) ? Qo : (z == 1) ? Ko : Vo;

  __shared__ __align__(16) u16 As[128 * 32];
  __shared__ __align__(16) u16 Bs[128 * 32];
  int tid = threadIdx.x;
  int m0 = blockIdx.y * 128, n0 = blockIdx.x * 128;
  int w = tid >> 6, l = tid & 63;
  int wm = w >> 1, wn = w & 1;
  const int4* Xs = (const int4*)X;
  const int4* Ws = (const int4*)Wt;
  int4* As4 = (int4*)As;
  int4* Bs4 = (int4*)Bs;
  f32x4 acc[4][4] = {};
  for (int kt = 0; kt < 32; ++kt) {
    #pragma unroll
    for (int c = 0; c < 2; ++c) {
      int i = c * 256 + tid;              // 0..511 int4 chunks; dest = wave-uniform base + lane*16
      int row = i >> 2, kc = i & 3;
      __builtin_amdgcn_global_load_lds(
          (const __attribute__((address_space(1))) void*)&Xs[(size_t)(m0 + row) * 128 + kt * 4 + kc],
          (__attribute__((address_space(3))) void*)&As4[i], 16, 0, 0);
      __builtin_amdgcn_global_load_lds(
          (const __attribute__((address_space(1))) void*)&Ws[(size_t)(n0 + row) * 128 + kt * 4 + kc],
          (__attribute__((address_space(3))) void*)&Bs4[i], 16, 0, 0);
    }
    __syncthreads();
    bf16x8 a[4], bb[4];
    #pragma unroll
    for (int mc = 0; mc < 4; ++mc) a[mc]  = *(const bf16x8*)&As[(wm*64 + mc*16 + (l & 15)) * 32 + (l >> 4) * 8];
    #pragma unroll
    for (int nc = 0; nc < 4; ++nc) bb[nc] = *(const bf16x8*)&Bs[(wn*64 + nc*16 + (l & 15)) * 32 + (l >> 4) * 8];
    #pragma unroll
    for (int mc = 0; mc < 4; ++mc)
      #pragma unroll
      for (int nc = 0; nc < 4; ++nc)
        acc[mc][nc] = __builtin_amdgcn_mfma_f32_16x16x32_bf16(a[mc], bb[nc], acc[mc][nc], 0, 0, 0);
    __syncthreads();
  }
  #pragma unroll
  for (int nc = 0; nc < 4; ++nc) {
    int n = n0 + wn * 64 + nc * 16 + (l & 15);
    float bvv = bias[n];
    int h = n >> 6, d = n & 63;
    #pragma unroll
    for (int mc = 0; mc < 4; ++mc) {
      int srow_base = m0 + wm * 64 + mc * 16 + (l >> 4) * 4;
      if (z == 2) {
        // V^T write: Vt[(b*16+h)*64 + d][s..s+3] — 4 consecutive u16 = one 8B store
        int b = srow_base >> 10, s = srow_base & 1023;   // srow_base % 4 == 0, no b-crossing in r
        ushort4 vv;
        vv.x = f2bf(acc[mc][nc][0] + bvv);
        vv.y = f2bf(acc[mc][nc][1] + bvv);
        vv.z = f2bf(acc[mc][nc][2] + bvv);
        vv.w = f2bf(acc[mc][nc][3] + bvv);
        *(ushort4*)&outp[((size_t)((b * 16 + h) * 64 + d)) * 1024 + s] = vv;
      } else {
        #pragma unroll
        for (int r = 0; r < 4; ++r) {
          int sm = srow_base + r;
          int b = sm >> 10, s = sm & 1023;
          outp[((size_t)((b * 16 + h) * 1024 + s)) * 64 + d] = f2bf(acc[mc][nc][r] + bvv);
        }
      }
    }
  }
}

// ---------------- fused double-softmax attention, v10 ----------------
// No persistent score array: pass A = QK^T + ONLINE (m,z) softmax accumulation
// (discard scores); pass B = RECOMPUTE QK^T (K re-staged into KVl[0], V into
// KVl[1], single-buffered, 2 barriers/tile) -> p1 = exp2(s - lm) ->
// p2 = exp2(mkl - L2E*p1) -> PV. kappa-permuted key order makes the fresh
// p-registers exactly the PV A-fragments. Frees ~64 persistent regs (sp[] gone)
// -> total regs ~110/wave -> 4 waves/SIMD; LDS ~33KB -> 4 blocks/CU.
// grid 4096 = 8 xcd x 16 bh x 32 qt; 4 waves = 2 qg x 2 kh.
__global__ __launch_bounds__(256, 2) void attn10(const u16* __restrict__ Q, const u16* __restrict__ K,
                                                 const u16* __restrict__ Vt, const float* __restrict__ mask,
                                                 const int* __restrict__ clp, float* __restrict__ out) {
  __shared__ __align__(16) u16 KVl[2][8192];   // pass A: K dbuf; pass B: K in [0], V in [1]
  __shared__ float m1p[2][2][16];
  __shared__ float z1p[2][2][16];
  __shared__ float z2p[2][2][16];

  int bid = blockIdx.x;
  int xcd = bid & 7, idx = bid >> 3;
  int bh = xcd * 16 + (idx >> 5);   // 32 q-tile blocks share (b,h) within an XCD
  int qt = idx & 31;
  int b = bh >> 4, h = bh & 15;
  int tid = threadIdx.x;
  int w = tid >> 6, l = tid & 63;
  int lq = l & 15, g = l >> 4;
  int qg = w >> 1, kh = w & 1;
  int qb = qt * 32 + qg * 16;

  const float* mrow = mask + b * 1024;
  const u16* Kb = K + (size_t)bh * 65536;
  const u16* Vb = Vt + (size_t)bh * 65536;
  int cl = clp[0];

  // K stage: dest chunk i=(row,ch of 8); src chunk = ch ^ F(row), F = (row&3)|(((row>>3 ^ row>>4)&1)<<2)
#define STAGE_K(bi, t) do {                                                                  \
    _Pragma("unroll")                                                                        \
    for (int c_ = 0; c_ < 4; ++c_) {                                                         \
      int i_ = c_ * 256 + tid; int row_ = i_ >> 3, ch_ = i_ & 7;                             \
      int f_ = (row_ & 3) | ((((row_ >> 3) ^ (row_ >> 4)) & 1) << 2);                        \
      __builtin_amdgcn_global_load_lds(                                                      \
        (const __attribute__((address_space(1))) void*)(Kb + (size_t)((t) * 128 + row_) * 64 + ((ch_ ^ f_) * 8)), \
        (__attribute__((address_space(3))) void*)&KVl[bi][i_ * 8], 16, 0, 0);                \
    } } while (0)

  // V stage (128-key tile): row=d (0..63, 16 chunks of 8 keys); src chunk = ch ^ (row&15)
#define STAGE_V(bi, t) do {                                                                  \
    _Pragma("unroll")                                                                        \
    for (int c_ = 0; c_ < 4; ++c_) {                                                         \
      int i_ = c_ * 256 + tid; int row_ = i_ >> 4, ch_ = i_ & 15;                            \
      __builtin_amdgcn_global_load_lds(                                                      \
        (const __attribute__((address_space(1))) void*)(Vb + (size_t)row_ * 1024 + (t) * 128 + ((ch_ ^ (row_ & 15)) * 8)), \
        (__attribute__((address_space(3))) void*)&KVl[bi][i_ * 8], 16, 0, 0);                \
    } } while (0)

  STAGE_K(0, 0);

  const u16* Qp = Q + ((size_t)bh * 1024 + qb + lq) * 64 + g * 8;
  bf16x8 qf0 = *(const bf16x8*)Qp;
  bf16x8 qf1 = *(const bf16x8*)(Qp + 32);

  __syncthreads();   // K0 staged

  // ---- pass A: swapped QK^T + online (m,z); scores discarded ----
  const float sl2e = 0.125f * L2E;
  float m_run = -1e30f, z_run = 0.f;
  int cur = 0;
  #pragma unroll
  for (int t = 0; t < 8; ++t) {
    if (t < 7) STAGE_K(cur ^ 1, t + 1);
    else       STAGE_K(0, 0);            // prefetch pass-B K tile 0 (KVl[0] dead at t=7: cur==1)
    #pragma unroll
    for (int ct = 0; ct < 4; ++ct) {
      int m = ct >> 1, c = ct & 1;
      int row128 = kh * 64 + m * 32 + ((lq >> 2) << 3) + c * 4 + (lq & 3);   // kappa
      int F = (row128 & 3) | ((((row128 >> 3) ^ (row128 >> 4)) & 1) << 2);
      bf16x8 kf0 = *(const bf16x8*)&KVl[cur][row128 * 64 + ((g ^ F) * 8)];
      bf16x8 kf1 = *(const bf16x8*)&KVl[cur][row128 * 64 + (((g + 4) ^ F) * 8)];
      f32x4 tt = {0.f, 0.f, 0.f, 0.f};
      tt = __builtin_amdgcn_mfma_f32_16x16x32_bf16(kf0, qf0, tt, 0, 0, 0);
      tt = __builtin_amdgcn_mfma_f32_16x16x32_bf16(kf1, qf1, tt, 0, 0, 0);
      float4 mk = *(const float4*)(mrow + t * 128 + kh * 64 + m * 32 + g * 8 + c * 4);
      float s0 = fmaf(tt[0], sl2e, mk.x * L2E);
      float s1 = fmaf(tt[1], sl2e, mk.y * L2E);
      float s2 = fmaf(tt[2], sl2e, mk.z * L2E);
      float s3 = fmaf(tt[3], sl2e, mk.w * L2E);
      float tmax = fmaxf(fmaxf(s0, s1), fmaxf(s2, s3));
      float mn = fmaxf(m_run, tmax);
      float e0 = __builtin_amdgcn_exp2f(s0 - mn);
      float e1 = __builtin_amdgcn_exp2f(s1 - mn);
      float e2 = __builtin_amdgcn_exp2f(s2 - mn);
      float e3 = __builtin_amdgcn_exp2f(s3 - mn);
      float sc = __builtin_amdgcn_exp2f(m_run - mn);
      z_run = fmaf(z_run, sc, (e0 + e1) + (e2 + e3));
      m_run = mn;
    }
    __syncthreads();
    cur ^= 1;
  }
  // KVl[1] dead now (t=7 computed from it, barrier passed) -> prefetch pass-B V tile 0
  STAGE_V(1, 0);

  // ---- merge (m,z) across g-groups (shfl) and kh waves (LDS) -> lm = m1 + log2(Z1) ----
  {
    float mo = __shfl_xor(m_run, 16), zo = __shfl_xor(z_run, 16);
    float mn = fmaxf(m_run, mo);
    z_run = z_run * __builtin_amdgcn_exp2f(m_run - mn) + zo * __builtin_amdgcn_exp2f(mo - mn);
    m_run = mn;
    mo = __shfl_xor(m_run, 32); zo = __shfl_xor(z_run, 32);
    mn = fmaxf(m_run, mo);
    z_run = z_run * __builtin_amdgcn_exp2f(m_run - mn) + zo * __builtin_amdgcn_exp2f(mo - mn);
    m_run = mn;
  }
  if (l < 16) { m1p[kh][qg][l] = m_run; z1p[kh][qg][l] = z_run; }
  __syncthreads();
  float lm;
  {
    float ma = m1p[0][qg][lq], mb = m1p[1][qg][lq];
    float m1 = fmaxf(ma, mb);
    float Z1 = z1p[0][qg][lq] * __builtin_amdgcn_exp2f(ma - m1)
             + z1p[1][qg][lq] * __builtin_amdgcn_exp2f(mb - m1);
    lm = m1 + __builtin_amdgcn_logf(Z1);   // v_log_f32 = log2
  }

  // ---- pass B: recompute QK^T, p1 = exp2(s-lm), p2 = exp2(mkl - L2E*p1), PV ----
  f32x4 acc[4] = {};
  float z2 = 0.f;
  #pragma unroll
  for (int t = 0; t < 8; ++t) {
    // tile t: K in KVl[0], V in KVl[1] (t=0 prefetched above; drained by merge barriers)
    #pragma unroll
    for (int mm = 0; mm < 2; ++mm) {
      u32x4 pk;
      #pragma unroll
      for (int c = 0; c < 2; ++c) {
        int row128 = kh * 64 + mm * 32 + ((lq >> 2) << 3) + c * 4 + (lq & 3);
        int F = (row128 & 3) | ((((row128 >> 3) ^ (row128 >> 4)) & 1) << 2);
        bf16x8 kf0 = *(const bf16x8*)&KVl[0][row128 * 64 + ((g ^ F) * 8)];
        bf16x8 kf1 = *(const bf16x8*)&KVl[0][row128 * 64 + (((g + 4) ^ F) * 8)];
        f32x4 tt = {0.f, 0.f, 0.f, 0.f};
        tt = __builtin_amdgcn_mfma_f32_16x16x32_bf16(kf0, qf0, tt, 0, 0, 0);
        tt = __builtin_amdgcn_mfma_f32_16x16x32_bf16(kf1, qf1, tt, 0, 0, 0);
        float4 mk = *(const float4*)(mrow + t * 128 + kh * 64 + mm * 32 + g * 8 + c * 4);
        float mkl0 = mk.x * L2E, mkl1 = mk.y * L2E, mkl2 = mk.z * L2E, mkl3 = mk.w * L2E;
        float p10 = __builtin_amdgcn_exp2f(fmaf(tt[0], sl2e, mkl0) - lm);
        float p11 = __builtin_amdgcn_exp2f(fmaf(tt[1], sl2e, mkl1) - lm);
        float p12 = __builtin_amdgcn_exp2f(fmaf(tt[2], sl2e, mkl2) - lm);
        float p13 = __builtin_amdgcn_exp2f(fmaf(tt[3], sl2e, mkl3) - lm);
        if (cl) {
          float p20 = __builtin_amdgcn_exp2f(fmaf(-L2E, p10, mkl0));
          float p21 = __builtin_amdgcn_exp2f(fmaf(-L2E, p11, mkl1));
          float p22 = __builtin_amdgcn_exp2f(fmaf(-L2E, p12, mkl2));
          float p23 = __builtin_amdgcn_exp2f(fmaf(-L2E, p13, mkl3));
          z2 += (p20 + p21) + (p22 + p23);
          pk[c * 2 + 0] = pkbf(p20, p21);
          pk[c * 2 + 1] = pkbf(p22, p23);
        } else {
          pk[c * 2 + 0] = pkbf(p10, p11);   // normalized probs1 -> epilogue scale = 1
          pk[c * 2 + 1] = pkbf(p12, p13);
        }
      }
      bf16x8 pf = __builtin_bit_cast(bf16x8, pk);
      #pragma unroll
      for (int dc = 0; dc < 4; ++dc) {
        int row = dc * 16 + lq;
        int ch = (kh * 8 + mm * 4 + g) ^ (row & 15);
        bf16x8 vf = *(const bf16x8*)&KVl[1][row * 128 + ch * 8];
        acc[dc] = __builtin_amdgcn_mfma_f32_16x16x32_bf16(pf, vf, acc[dc], 0, 0, 0);
      }
    }
    __syncthreads();                       // all reads of tile t done
    if (t < 7) {
      STAGE_K(0, t + 1);
      STAGE_V(1, t + 1);
      __syncthreads();                     // tile t+1 landed + visible
    }
  }

  // ---- epilogue: cross-kh reduce acc (overlay dead KVl[0]) + scale ----
  z2 += __shfl_xor(z2, 16);
  z2 += __shfl_xor(z2, 32);
  if (l < 16) z2p[kh][qg][l] = z2;
  float* redF = (float*)&KVl[0][0];    // [2 qg][16 q][68 d-stride] = 8.7KB
  if (kh == 1) {
    #pragma unroll
    for (int dc = 0; dc < 4; ++dc)
      #pragma unroll
      for (int r = 0; r < 4; ++r)
        redF[qg * 1088 + (g * 4 + r) * 68 + dc * 16 + lq] = acc[dc][r];
  }
  __syncthreads();
  if (kh == 0) {
    float Z2 = z2p[0][qg][lq] + z2p[1][qg][lq];
    float phi = cl ? __builtin_amdgcn_rcpf(Z2) : 1.0f;   // value for q-row lq
    #pragma unroll
    for (int r = 0; r < 4; ++r) {
      float ph = __shfl(phi, g * 4 + r);
      size_t orow = ((size_t)(b * 1024 + qb + g * 4 + r)) * 1024 + h * 64;
      #pragma unroll
      for (int dc = 0; dc < 4; ++dc) {
        float o = acc[dc][r] + redF[qg * 1088 + (g * 4 + r) * 68 + dc * 16 + lq];
        out[orow + dc * 16 + lq] = o * ph;
      }
    }
  }
#undef STAGE_K
#undef STAGE_V
}

extern "C" void kernel_launch(void* const* d_in, const int* in_sizes, int n_in,
                              void* d_out, int out_size, void* d_ws, size_t ws_size,
                              hipStream_t stream) {
  const float* s1   = (const float*)d_in[0];
  const float* s2   = (const float*)d_in[1];
  const float* mask = (const float*)d_in[2];
  const float* Wq   = (const float*)d_in[3];
  const float* bq   = (const float*)d_in[4];
  const float* Wk   = (const float*)d_in[5];
  const float* bk   = (const float*)d_in[6];
  const float* Wv   = (const float*)d_in[7];
  const float* bv   = (const float*)d_in[8];
  const int*   cl   = (const int*)d_in[9];
  float* out = (float*)d_out;

  // ws layout (u16 elements): X1[8M] X2[8M] Wtq[1M] Wtk[1M] Wtv[1M] Q[8M] K[8M] Vt[8M]
  u16* ws  = (u16*)d_ws;
  const size_t M1 = 1024 * 1024;
  u16* X1  = ws;
  u16* X2  = ws + 8 * M1;
  u16* Wtq = ws + 16 * M1;
  u16* Wtk = Wtq + M1;
  u16* Wtv = Wtk + M1;
  u16* Qb  = Wtv + M1;
  u16* Kb  = Qb + 8 * M1;
  u16* Vtb = Kb + 8 * M1;   // V^T written directly by qkv_gemm3 (z==2)

  conv_f32_bf16<<<2048, 256, 0, stream>>>(s1, X1, 2097152);
  conv_f32_bf16<<<2048, 256, 0, stream>>>(s2, X2, 2097152);
  dim3 wtb(32, 8);
  wtrans<<<dim3(32, 32), wtb, 0, stream>>>(Wq, Wtq);
  wtrans<<<dim3(32, 32), wtb, 0, stream>>>(Wk, Wtk);
  wtrans<<<dim3(32, 32), wtb, 0, stream>>>(Wv, Wtv);
  qkv_gemm3<<<dim3(8, 64, 3), 256, 0, stream>>>(X1, X2, Wtq, Wtk, Wtv, bq, bk, bv, Qb, Kb, Vtb);
  attn10<<<4096, 256, 0, stream>>>(Qb, Kb, Vtb, mask, cl, out);
}

// Round 10
// 220.990 us; speedup vs baseline: 1.6546x; 1.1304x over previous
//
#include <hip/hip_runtime.h>
#include <hip/hip_bf16.h>

typedef unsigned short u16;
typedef __attribute__((ext_vector_type(8))) short bf16x8;   // 8 bf16 = 4 VGPRs (MFMA A/B frag)
typedef __attribute__((ext_vector_type(4))) float f32x4;    // MFMA C/D frag
typedef __attribute__((ext_vector_type(4))) unsigned u32x4;

#define L2E 1.4426950408889634f

__device__ __forceinline__ u16 f2bf(float f) {
  unsigned u = __float_as_uint(f);
  u = u + 0x7fffu + ((u >> 16) & 1u);   // RNE
  return (u16)(u >> 16);
}
__device__ __forceinline__ unsigned pkbf(float a, float b) {   // low = a, high = b (RNE)
  return ((unsigned)f2bf(b) << 16) | f2bf(a);
}
__device__ __forceinline__ unsigned cvtpk(float a, float b) {  // low = bf16(a), high = bf16(b), HW RNE
  unsigned r;
  asm("v_cvt_pk_bf16_f32 %0, %1, %2" : "=v"(r) : "v"(a), "v"(b));
  return r;
}

// ---------------- prep: f32 -> bf16 elementwise ----------------
__global__ void conv_f32_bf16(const float* __restrict__ in, u16* __restrict__ out, int n4) {
  int i = blockIdx.x * blockDim.x + threadIdx.x;
  int stride = gridDim.x * blockDim.x;
  for (; i < n4; i += stride) {
    float4 v = ((const float4*)in)[i];
    ushort4 o = make_ushort4(f2bf(v.x), f2bf(v.y), f2bf(v.z), f2bf(v.w));
    ((ushort4*)out)[i] = o;
  }
}

// ---------------- prep: W[k][n] f32 -> Wt[n][k] bf16 (3 weights via blockIdx.z) ----------------
__global__ void wtrans3(const float* __restrict__ Wq, const float* __restrict__ Wk,
                        const float* __restrict__ Wv,
                        u16* __restrict__ Wtq, u16* __restrict__ Wtk, u16* __restrict__ Wtv) {
  int z = blockIdx.z;
  const float* W = (z == 0) ? Wq : (z == 1) ? Wk : Wv;
  u16* Wt = (z == 0) ? Wtq : (z == 1) ? Wtk : Wtv;
  __shared__ float T[32][33];
  int k0 = blockIdx.y * 32, n0 = blockIdx.x * 32;
  int tx = threadIdx.x, ty = threadIdx.y;       // (32,8)
  #pragma unroll
  for (int j = 0; j < 4; ++j) T[ty + 8*j][tx] = W[(size_t)(k0 + ty + 8*j) * 1024 + n0 + tx];
  __syncthreads();
  #pragma unroll
  for (int j = 0; j < 4; ++j) Wt[(size_t)(n0 + ty + 8*j) * 1024 + k0 + tx] = f2bf(T[tx][ty + 8*j]);
}

// ---------------- QKV projection GEMM (3 fused via blockIdx.z), global_load_lds staging ----------------
// z==2 (V projection) writes V^T [B,H,64,S] directly.
__global__ __launch_bounds__(256) void qkv_gemm3(const u16* __restrict__ X1, const u16* __restrict__ X2,
                                                 const u16* __restrict__ Wtq, const u16* __restrict__ Wtk,
                                                 const u16* __restrict__ Wtv,
                                                 const float* __restrict__ bq, const float* __restrict__ bk,
                                                 const float* __restrict__ bv,
                                                 u16* __restrict__ Qo, u16* __restrict__ Ko, u16* __restrict__ Vo) {
  int z = blockIdx.z;
  const u16* X   = (z == 0) ? X1 : X2;
  const u16* Wt  = (z == 0) ? Wtq : (z == 1) ? Wtk : Wtv;
  const float* bias = (z == 0) ? bq : (z == 1) ? bk : bv;
  u16* outp = (z == 0) ? Qo : (z == 1) ? Ko : Vo;

  __shared__ __align__(16) u16 As[128 * 32];
  __shared__ __align__(16) u16 Bs[128 * 32];
  int tid = threadIdx.x;
  int m0 = blockIdx.y * 128, n0 = blockIdx.x * 128;
  int w = tid >> 6, l = tid & 63;
  int wm = w >> 1, wn = w & 1;
  const int4* Xs = (const int4*)X;
  const int4* Ws = (const int4*)Wt;
  int4* As4 = (int4*)As;
  int4* Bs4 = (int4*)Bs;
  f32x4 acc[4][4] = {};
  for (int kt = 0; kt < 32; ++kt) {
    #pragma unroll
    for (int c = 0; c < 2; ++c) {
      int i = c * 256 + tid;              // 0..511 int4 chunks; dest = wave-uniform base + lane*16
      int row = i >> 2, kc = i & 3;
      __builtin_amdgcn_global_load_lds(
          (const __attribute__((address_space(1))) void*)&Xs[(size_t)(m0 + row) * 128 + kt * 4 + kc],
          (__attribute__((address_space(3))) void*)&As4[i], 16, 0, 0);
      __builtin_amdgcn_global_load_lds(
          (const __attribute__((address_space(1))) void*)&Ws[(size_t)(n0 + row) * 128 + kt * 4 + kc],
          (__attribute__((address_space(3))) void*)&Bs4[i], 16, 0, 0);
    }
    __syncthreads();
    bf16x8 a[4], bb[4];
    #pragma unroll
    for (int mc = 0; mc < 4; ++mc) a[mc]  = *(const bf16x8*)&As[(wm*64 + mc*16 + (l & 15)) * 32 + (l >> 4) * 8];
    #pragma unroll
    for (int nc = 0; nc < 4; ++nc) bb[nc] = *(const bf16x8*)&Bs[(wn*64 + nc*16 + (l & 15)) * 32 + (l >> 4) * 8];
    #pragma unroll
    for (int mc = 0; mc < 4; ++mc)
      #pragma unroll
      for (int nc = 0; nc < 4; ++nc)
        acc[mc][nc] = __builtin_amdgcn_mfma_f32_16x16x32_bf16(a[mc], bb[nc], acc[mc][nc], 0, 0, 0);
    __syncthreads();
  }
  #pragma unroll
  for (int nc = 0; nc < 4; ++nc) {
    int n = n0 + wn * 64 + nc * 16 + (l & 15);
    float bvv = bias[n];
    int h = n >> 6, d = n & 63;
    #pragma unroll
    for (int mc = 0; mc < 4; ++mc) {
      int srow_base = m0 + wm * 64 + mc * 16 + (l >> 4) * 4;
      if (z == 2) {
        // V^T write: Vt[(b*16+h)*64 + d][s..s+3] — 4 consecutive u16 = one 8B store
        int b = srow_base >> 10, s = srow_base & 1023;   // srow_base % 4 == 0, no b-crossing in r
        ushort4 vv;
        vv.x = f2bf(acc[mc][nc][0] + bvv);
        vv.y = f2bf(acc[mc][nc][1] + bvv);
        vv.z = f2bf(acc[mc][nc][2] + bvv);
        vv.w = f2bf(acc[mc][nc][3] + bvv);
        *(ushort4*)&outp[((size_t)((b * 16 + h) * 64 + d)) * 1024 + s] = vv;
      } else {
        #pragma unroll
        for (int r = 0; r < 4; ++r) {
          int sm = srow_base + r;
          int b = sm >> 10, s = sm & 1023;
          outp[((size_t)((b * 16 + h) * 1024 + s)) * 64 + d] = f2bf(acc[mc][nc][r] + bvv);
        }
      }
    }
  }
}

// ---------------- fused double-softmax attention, v11 ----------------
// v10 structure (recompute QK^T, no persistent score regs) with instruction diet:
// (1) MAX-FREE softmax-1: scores = q.k/8 + mask, q,k ~ N(0,1) => |s*log2e| <~ 10,
//     mask <= 0 only shrinks exp2; Z1 in [1, ~5e5] fits fp32 comfortably -> the
//     online (m,z) rescale machinery is deleted; lm = log2(Z1).
// (2) maskL2[1024] f32 LDS = mask * log2e premultiplied (deletes per-use muls).
// (3) v_cvt_pk_bf16_f32 packs in pass B (1 instr vs ~11 per pair).
// grid 4096 = 8 xcd x 16 bh x 32 qt; 4 waves = 2 qg x 2 kh; LDS ~37.4KB.
__global__ __launch_bounds__(256, 3) void attn11(const u16* __restrict__ Q, const u16* __restrict__ K,
                                                 const u16* __restrict__ Vt, const float* __restrict__ mask,
                                                 const int* __restrict__ clp, float* __restrict__ out) {
  __shared__ __align__(16) u16 KVl[2][8192];   // pass A: K dbuf; pass B: K in [0], V in [1]
  __shared__ __align__(16) float maskL2[1024]; // mask * log2e
  __shared__ float z1p[2][2][16];
  __shared__ float z2p[2][2][16];

  int bid = blockIdx.x;
  int xcd = bid & 7, idx = bid >> 3;
  int bh = xcd * 16 + (idx >> 5);   // 32 q-tile blocks share (b,h) within an XCD
  int qt = idx & 31;
  int b = bh >> 4, h = bh & 15;
  int tid = threadIdx.x;
  int w = tid >> 6, l = tid & 63;
  int lq = l & 15, g = l >> 4;
  int qg = w >> 1, kh = w & 1;
  int qb = qt * 32 + qg * 16;

  const u16* Kb = K + (size_t)bh * 65536;
  const u16* Vb = Vt + (size_t)bh * 65536;
  int cl = clp[0];

  // K stage: dest chunk i=(row,ch of 8); src chunk = ch ^ F(row), F = (row&3)|(((row>>3 ^ row>>4)&1)<<2)
#define STAGE_K(bi, t) do {                                                                  \
    _Pragma("unroll")                                                                        \
    for (int c_ = 0; c_ < 4; ++c_) {                                                         \
      int i_ = c_ * 256 + tid; int row_ = i_ >> 3, ch_ = i_ & 7;                             \
      int f_ = (row_ & 3) | ((((row_ >> 3) ^ (row_ >> 4)) & 1) << 2);                        \
      __builtin_amdgcn_global_load_lds(                                                      \
        (const __attribute__((address_space(1))) void*)(Kb + (size_t)((t) * 128 + row_) * 64 + ((ch_ ^ f_) * 8)), \
        (__attribute__((address_space(3))) void*)&KVl[bi][i_ * 8], 16, 0, 0);                \
    } } while (0)

  // V stage (128-key tile): row=d (0..63, 16 chunks of 8 keys); src chunk = ch ^ (row&15)
#define STAGE_V(bi, t) do {                                                                  \
    _Pragma("unroll")                                                                        \
    for (int c_ = 0; c_ < 4; ++c_) {                                                         \
      int i_ = c_ * 256 + tid; int row_ = i_ >> 4, ch_ = i_ & 15;                            \
      __builtin_amdgcn_global_load_lds(                                                      \
        (const __attribute__((address_space(1))) void*)(Vb + (size_t)row_ * 1024 + (t) * 128 + ((ch_ ^ (row_ & 15)) * 8)), \
        (__attribute__((address_space(3))) void*)&KVl[bi][i_ * 8], 16, 0, 0);                \
    } } while (0)

  STAGE_K(0, 0);

  for (int i = tid; i < 1024; i += 256) maskL2[i] = mask[b * 1024 + i] * L2E;

  const u16* Qp = Q + ((size_t)bh * 1024 + qb + lq) * 64 + g * 8;
  bf16x8 qf0 = *(const bf16x8*)Qp;
  bf16x8 qf1 = *(const bf16x8*)(Qp + 32);

  __syncthreads();   // K0 staged + maskL2 ready

  // ---- pass A: swapped QK^T, plain Z1 = sum exp2(s) (max-free); scores discarded ----
  const float sl2e = 0.125f * L2E;
  float z_run = 0.f;
  int cur = 0;
  #pragma unroll
  for (int t = 0; t < 8; ++t) {
    if (t < 7) STAGE_K(cur ^ 1, t + 1);
    else       STAGE_K(0, 0);            // prefetch pass-B K tile 0 (KVl[0] dead at t=7: cur==1)
    #pragma unroll
    for (int ct = 0; ct < 4; ++ct) {
      int m = ct >> 1, c = ct & 1;
      int row128 = kh * 64 + m * 32 + ((lq >> 2) << 3) + c * 4 + (lq & 3);   // kappa
      int F = (row128 & 3) | ((((row128 >> 3) ^ (row128 >> 4)) & 1) << 2);
      bf16x8 kf0 = *(const bf16x8*)&KVl[cur][row128 * 64 + ((g ^ F) * 8)];
      bf16x8 kf1 = *(const bf16x8*)&KVl[cur][row128 * 64 + (((g + 4) ^ F) * 8)];
      f32x4 tt = {0.f, 0.f, 0.f, 0.f};
      tt = __builtin_amdgcn_mfma_f32_16x16x32_bf16(kf0, qf0, tt, 0, 0, 0);
      tt = __builtin_amdgcn_mfma_f32_16x16x32_bf16(kf1, qf1, tt, 0, 0, 0);
      const float4 mk = *(const float4*)&maskL2[t * 128 + kh * 64 + m * 32 + g * 8 + c * 4];
      float e0 = __builtin_amdgcn_exp2f(fmaf(tt[0], sl2e, mk.x));
      float e1 = __builtin_amdgcn_exp2f(fmaf(tt[1], sl2e, mk.y));
      float e2 = __builtin_amdgcn_exp2f(fmaf(tt[2], sl2e, mk.z));
      float e3 = __builtin_amdgcn_exp2f(fmaf(tt[3], sl2e, mk.w));
      z_run += (e0 + e1) + (e2 + e3);
    }
    __syncthreads();
    cur ^= 1;
  }
  // KVl[1] dead now -> prefetch pass-B V tile 0
  STAGE_V(1, 0);

  // ---- merge Z1 across g-groups (shfl) and kh waves (LDS) -> lm = log2(Z1) ----
  z_run += __shfl_xor(z_run, 16);
  z_run += __shfl_xor(z_run, 32);
  if (l < 16) z1p[kh][qg][l] = z_run;
  __syncthreads();
  float lm = __builtin_amdgcn_logf(z1p[0][qg][lq] + z1p[1][qg][lq]);   // v_log_f32 = log2

  // ---- pass B: recompute QK^T, p1 = exp2(s-lm), p2 = exp2(mkl - L2E*p1), PV ----
  f32x4 acc[4] = {};
  float z2 = 0.f;
  #pragma unroll
  for (int t = 0; t < 8; ++t) {
    // tile t: K in KVl[0], V in KVl[1] (t=0 prefetched above; drained by merge barrier)
    #pragma unroll
    for (int mm = 0; mm < 2; ++mm) {
      u32x4 pk;
      #pragma unroll
      for (int c = 0; c < 2; ++c) {
        int row128 = kh * 64 + mm * 32 + ((lq >> 2) << 3) + c * 4 + (lq & 3);
        int F = (row128 & 3) | ((((row128 >> 3) ^ (row128 >> 4)) & 1) << 2);
        bf16x8 kf0 = *(const bf16x8*)&KVl[0][row128 * 64 + ((g ^ F) * 8)];
        bf16x8 kf1 = *(const bf16x8*)&KVl[0][row128 * 64 + (((g + 4) ^ F) * 8)];
        f32x4 tt = {0.f, 0.f, 0.f, 0.f};
        tt = __builtin_amdgcn_mfma_f32_16x16x32_bf16(kf0, qf0, tt, 0, 0, 0);
        tt = __builtin_amdgcn_mfma_f32_16x16x32_bf16(kf1, qf1, tt, 0, 0, 0);
        const float4 mk = *(const float4*)&maskL2[t * 128 + kh * 64 + mm * 32 + g * 8 + c * 4];
        float p10 = __builtin_amdgcn_exp2f(fmaf(tt[0], sl2e, mk.x) - lm);
        float p11 = __builtin_amdgcn_exp2f(fmaf(tt[1], sl2e, mk.y) - lm);
        float p12 = __builtin_amdgcn_exp2f(fmaf(tt[2], sl2e, mk.z) - lm);
        float p13 = __builtin_amdgcn_exp2f(fmaf(tt[3], sl2e, mk.w) - lm);
        if (cl) {
          float p20 = __builtin_amdgcn_exp2f(fmaf(-L2E, p10, mk.x));
          float p21 = __builtin_amdgcn_exp2f(fmaf(-L2E, p11, mk.y));
          float p22 = __builtin_amdgcn_exp2f(fmaf(-L2E, p12, mk.z));
          float p23 = __builtin_amdgcn_exp2f(fmaf(-L2E, p13, mk.w));
          z2 += (p20 + p21) + (p22 + p23);
          pk[c * 2 + 0] = cvtpk(p20, p21);
          pk[c * 2 + 1] = cvtpk(p22, p23);
        } else {
          pk[c * 2 + 0] = cvtpk(p10, p11);   // normalized probs1 -> epilogue scale = 1
          pk[c * 2 + 1] = cvtpk(p12, p13);
        }
      }
      bf16x8 pf = __builtin_bit_cast(bf16x8, pk);
      #pragma unroll
      for (int dc = 0; dc < 4; ++dc) {
        int row = dc * 16 + lq;
        int ch = (kh * 8 + mm * 4 + g) ^ (row & 15);
        bf16x8 vf = *(const bf16x8*)&KVl[1][row * 128 + ch * 8];
        acc[dc] = __builtin_amdgcn_mfma_f32_16x16x32_bf16(pf, vf, acc[dc], 0, 0, 0);
      }
    }
    __syncthreads();                       // all reads of tile t done
    if (t < 7) {
      STAGE_K(0, t + 1);
      STAGE_V(1, t + 1);
      __syncthreads();                     // tile t+1 landed + visible
    }
  }

  // ---- epilogue: cross-kh reduce acc (overlay dead KVl[0]) + scale ----
  z2 += __shfl_xor(z2, 16);
  z2 += __shfl_xor(z2, 32);
  if (l < 16) z2p[kh][qg][l] = z2;
  float* redF = (float*)&KVl[0][0];    // [2 qg][16 q][68 d-stride] = 8.7KB
  if (kh == 1) {
    #pragma unroll
    for (int dc = 0; dc < 4; ++dc)
      #pragma unroll
      for (int r = 0; r < 4; ++r)
        redF[qg * 1088 + (g * 4 + r) * 68 + dc * 16 + lq] = acc[dc][r];
  }
  __syncthreads();
  if (kh == 0) {
    float Z2 = z2p[0][qg][lq] + z2p[1][qg][lq];
    float phi = cl ? __builtin_amdgcn_rcpf(Z2) : 1.0f;   // value for q-row lq
    #pragma unroll
    for (int r = 0; r < 4; ++r) {
      float ph = __shfl(phi, g * 4 + r);
      size_t orow = ((size_t)(b * 1024 + qb + g * 4 + r)) * 1024 + h * 64;
      #pragma unroll
      for (int dc = 0; dc < 4; ++dc) {
        float o = acc[dc][r] + redF[qg * 1088 + (g * 4 + r) * 68 + dc * 16 + lq];
        out[orow + dc * 16 + lq] = o * ph;
      }
    }
  }
#undef STAGE_K
#undef STAGE_V
}

extern "C" void kernel_launch(void* const* d_in, const int* in_sizes, int n_in,
                              void* d_out, int out_size, void* d_ws, size_t ws_size,
                              hipStream_t stream) {
  const float* s1   = (const float*)d_in[0];
  const float* s2   = (const float*)d_in[1];
  const float* mask = (const float*)d_in[2];
  const float* Wq   = (const float*)d_in[3];
  const float* bq   = (const float*)d_in[4];
  const float* Wk   = (const float*)d_in[5];
  const float* bk   = (const float*)d_in[6];
  const float* Wv   = (const float*)d_in[7];
  const float* bv   = (const float*)d_in[8];
  const int*   cl   = (const int*)d_in[9];
  float* out = (float*)d_out;

  // ws layout (u16 elements): X1[8M] X2[8M] Wtq[1M] Wtk[1M] Wtv[1M] Q[8M] K[8M] Vt[8M]
  u16* ws  = (u16*)d_ws;
  const size_t M1 = 1024 * 1024;
  u16* X1  = ws;
  u16* X2  = ws + 8 * M1;
  u16* Wtq = ws + 16 * M1;
  u16* Wtk = Wtq + M1;
  u16* Wtv = Wtk + M1;
  u16* Qb  = Wtv + M1;
  u16* Kb  = Qb + 8 * M1;
  u16* Vtb = Kb + 8 * M1;   // V^T written directly by qkv_gemm3 (z==2)

  conv_f32_bf16<<<2048, 256, 0, stream>>>(s1, X1, 2097152);
  conv_f32_bf16<<<2048, 256, 0, stream>>>(s2, X2, 2097152);
  wtrans3<<<dim3(32, 32, 3), dim3(32, 8), 0, stream>>>(Wq, Wk, Wv, Wtq, Wtk, Wtv);
  qkv_gemm3<<<dim3(8, 64, 3), 256, 0, stream>>>(X1, X2, Wtq, Wtk, Wtv, bq, bk, bv, Qb, Kb, Vtb);
  attn11<<<4096, 256, 0, stream>>>(Qb, Kb, Vtb, mask, cl, out);
}

// Round 11
// 212.602 us; speedup vs baseline: 1.7199x; 1.0394x over previous
//
#include <hip/hip_runtime.h>
#include <hip/hip_bf16.h>

typedef unsigned short u16;
typedef __attribute__((ext_vector_type(8))) short bf16x8;   // 8 bf16 = 4 VGPRs (MFMA A/B frag)
typedef __attribute__((ext_vector_type(4))) float f32x4;    // MFMA C/D frag
typedef __attribute__((ext_vector_type(4))) unsigned u32x4;

#define L2E 1.4426950408889634f

__device__ __forceinline__ u16 f2bf(float f) {
  unsigned u = __float_as_uint(f);
  u = u + 0x7fffu + ((u >> 16) & 1u);   // RNE
  return (u16)(u >> 16);
}
__device__ __forceinline__ unsigned cvtpk(float a, float b) {  // low = bf16(a), high = bf16(b), HW RNE
  unsigned r;
  asm("v_cvt_pk_bf16_f32 %0, %1, %2" : "=v"(r) : "v"(a), "v"(b));
  return r;
}

// ---------------- prep: f32 -> bf16 elementwise ----------------
__global__ void conv_f32_bf16(const float* __restrict__ in, u16* __restrict__ out, int n4) {
  int i = blockIdx.x * blockDim.x + threadIdx.x;
  int stride = gridDim.x * blockDim.x;
  for (; i < n4; i += stride) {
    float4 v = ((const float4*)in)[i];
    ushort4 o = make_ushort4(f2bf(v.x), f2bf(v.y), f2bf(v.z), f2bf(v.w));
    ((ushort4*)out)[i] = o;
  }
}

// ---------------- prep: W[k][n] f32 -> Wt[n][k] bf16 (3 weights via blockIdx.z) ----------------
__global__ void wtrans3(const float* __restrict__ Wq, const float* __restrict__ Wk,
                        const float* __restrict__ Wv,
                        u16* __restrict__ Wtq, u16* __restrict__ Wtk, u16* __restrict__ Wtv) {
  int z = blockIdx.z;
  const float* W = (z == 0) ? Wq : (z == 1) ? Wk : Wv;
  u16* Wt = (z == 0) ? Wtq : (z == 1) ? Wtk : Wtv;
  __shared__ float T[32][33];
  int k0 = blockIdx.y * 32, n0 = blockIdx.x * 32;
  int tx = threadIdx.x, ty = threadIdx.y;       // (32,8)
  #pragma unroll
  for (int j = 0; j < 4; ++j) T[ty + 8*j][tx] = W[(size_t)(k0 + ty + 8*j) * 1024 + n0 + tx];
  __syncthreads();
  #pragma unroll
  for (int j = 0; j < 4; ++j) Wt[(size_t)(n0 + ty + 8*j) * 1024 + k0 + tx] = f2bf(T[tx][ty + 8*j]);
}

// ---------------- QKV projection GEMM (3 fused via blockIdx.z), global_load_lds staging ----------------
// z==2 (V projection) writes V^T [B,H,64,S] directly.
__global__ __launch_bounds__(256) void qkv_gemm3(const u16* __restrict__ X1, const u16* __restrict__ X2,
                                                 const u16* __restrict__ Wtq, const u16* __restrict__ Wtk,
                                                 const u16* __restrict__ Wtv,
                                                 const float* __restrict__ bq, const float* __restrict__ bk,
                                                 const float* __restrict__ bv,
                                                 u16* __restrict__ Qo, u16* __restrict__ Ko, u16* __restrict__ Vo) {
  int z = blockIdx.z;
  const u16* X   = (z == 0) ? X1 : X2;
  const u16* Wt  = (z == 0) ? Wtq : (z == 1) ? Wtk : Wtv;
  const float* bias = (z == 0) ? bq : (z == 1) ? bk : bv;
  u16* outp = (z == 0) ? Qo : (z == 1) ? Ko : Vo;

  __shared__ __align__(16) u16 As[128 * 32];
  __shared__ __align__(16) u16 Bs[128 * 32];
  int tid = threadIdx.x;
  int m0 = blockIdx.y * 128, n0 = blockIdx.x * 128;
  int w = tid >> 6, l = tid & 63;
  int wm = w >> 1, wn = w & 1;
  const int4* Xs = (const int4*)X;
  const int4* Ws = (const int4*)Wt;
  int4* As4 = (int4*)As;
  int4* Bs4 = (int4*)Bs;
  f32x4 acc[4][4] = {};
  for (int kt = 0; kt < 32; ++kt) {
    #pragma unroll
    for (int c = 0; c < 2; ++c) {
      int i = c * 256 + tid;              // 0..511 int4 chunks; dest = wave-uniform base + lane*16
      int row = i >> 2, kc = i & 3;
      __builtin_amdgcn_global_load_lds(
          (const __attribute__((address_space(1))) void*)&Xs[(size_t)(m0 + row) * 128 + kt * 4 + kc],
          (__attribute__((address_space(3))) void*)&As4[i], 16, 0, 0);
      __builtin_amdgcn_global_load_lds(
          (const __attribute__((address_space(1))) void*)&Ws[(size_t)(n0 + row) * 128 + kt * 4 + kc],
          (__attribute__((address_space(3))) void*)&Bs4[i], 16, 0, 0);
    }
    __syncthreads();
    bf16x8 a[4], bb[4];
    #pragma unroll
    for (int mc = 0; mc < 4; ++mc) a[mc]  = *(const bf16x8*)&As[(wm*64 + mc*16 + (l & 15)) * 32 + (l >> 4) * 8];
    #pragma unroll
    for (int nc = 0; nc < 4; ++nc) bb[nc] = *(const bf16x8*)&Bs[(wn*64 + nc*16 + (l & 15)) * 32 + (l >> 4) * 8];
    #pragma unroll
    for (int mc = 0; mc < 4; ++mc)
      #pragma unroll
      for (int nc = 0; nc < 4; ++nc)
        acc[mc][nc] = __builtin_amdgcn_mfma_f32_16x16x32_bf16(a[mc], bb[nc], acc[mc][nc], 0, 0, 0);
    __syncthreads();
  }
  #pragma unroll
  for (int nc = 0; nc < 4; ++nc) {
    int n = n0 + wn * 64 + nc * 16 + (l & 15);
    float bvv = bias[n];
    int h = n >> 6, d = n & 63;
    #pragma unroll
    for (int mc = 0; mc < 4; ++mc) {
      int srow_base = m0 + wm * 64 + mc * 16 + (l >> 4) * 4;
      if (z == 2) {
        int b = srow_base >> 10, s = srow_base & 1023;   // srow_base % 4 == 0, no b-crossing in r
        ushort4 vv;
        vv.x = f2bf(acc[mc][nc][0] + bvv);
        vv.y = f2bf(acc[mc][nc][1] + bvv);
        vv.z = f2bf(acc[mc][nc][2] + bvv);
        vv.w = f2bf(acc[mc][nc][3] + bvv);
        *(ushort4*)&outp[((size_t)((b * 16 + h) * 64 + d)) * 1024 + s] = vv;
      } else {
        #pragma unroll
        for (int r = 0; r < 4; ++r) {
          int sm = srow_base + r;
          int b = sm >> 10, s = sm & 1023;
          outp[((size_t)((b * 16 + h) * 1024 + s)) * 64 + d] = f2bf(acc[mc][nc][r] + bvv);
        }
      }
    }
  }
}

// ---------------- fused double-softmax attention, v12 ----------------
// v11 skeleton (recompute QK^T, max-free Z1, maskL2, cvt_pk) with traffic diet:
// wave w = key-quarter [w*32, w*32+32) of every 128-key tile, ALL 32 q-rows
// (qg in {0,1} on the MFMA B-side) -> every K row / V column is LDS-read exactly
// once per block (v11 read each twice). Staging addresses + LDS read offsets
// hoisted out of the loops (affine in t). 4-way Z1/Z2 merges; 4-way acc
// reduction through dead KVl (3 x 8.5KB partials).
// grid 4096 = 8 xcd x 16 bh x 32 qt; 4 waves; LDS ~38KB.
__global__ __launch_bounds__(256, 3) void attn12(const u16* __restrict__ Q, const u16* __restrict__ K,
                                                 const u16* __restrict__ Vt, const float* __restrict__ mask,
                                                 const int* __restrict__ clp, float* __restrict__ out) {
  __shared__ __align__(16) u16 KVl[2][8192];   // pass A: K dbuf; pass B: K in [0], V in [1]; epilogue: redF
  __shared__ __align__(16) float maskL2[1024]; // mask * log2e
  __shared__ float z1p[4][32];
  __shared__ float z2p[4][32];

  int bid = blockIdx.x;
  int xcd = bid & 7, idx = bid >> 3;
  int bh = xcd * 16 + (idx >> 5);   // 32 q-tile blocks share (b,h) within an XCD
  int qt = idx & 31;
  int b = bh >> 4, h = bh & 15;
  int tid = threadIdx.x;
  int w = tid >> 6, l = tid & 63;
  int lq = l & 15, g = l >> 4;
  int qb = qt * 32;

  const u16* Kb = K + (size_t)bh * 65536;
  const u16* Vb = Vt + (size_t)bh * 65536;
  int cl = clp[0];

  // ---- hoisted staging addresses (affine in t) ----
  const u16* kS[4]; int kD[4];
  #pragma unroll
  for (int c_ = 0; c_ < 4; ++c_) {
    int i_ = c_ * 256 + tid, row_ = i_ >> 3, ch_ = i_ & 7;
    int f_ = (row_ & 3) | ((((row_ >> 3) ^ (row_ >> 4)) & 1) << 2);
    kS[c_] = Kb + row_ * 64 + (ch_ ^ f_) * 8;
    kD[c_] = i_ * 8;
  }
  const u16* vS[4]; int vD[4];
  #pragma unroll
  for (int c_ = 0; c_ < 4; ++c_) {
    int i_ = c_ * 256 + tid, row_ = i_ >> 4, ch_ = i_ & 15;
    vS[c_] = Vb + row_ * 1024 + (ch_ ^ (row_ & 15)) * 8;
    vD[c_] = i_ * 8;
  }

#define STAGE_K(bi, t) do { _Pragma("unroll")                                                 \
    for (int c_ = 0; c_ < 4; ++c_)                                                           \
      __builtin_amdgcn_global_load_lds(                                                      \
        (const __attribute__((address_space(1))) void*)(kS[c_] + (t) * 8192),                \
        (__attribute__((address_space(3))) void*)&KVl[bi][kD[c_]], 16, 0, 0); } while (0)

#define STAGE_V(bi, t) do { _Pragma("unroll")                                                 \
    for (int c_ = 0; c_ < 4; ++c_)                                                           \
      __builtin_amdgcn_global_load_lds(                                                      \
        (const __attribute__((address_space(1))) void*)(vS[c_] + (t) * 128),                 \
        (__attribute__((address_space(3))) void*)&KVl[bi][vD[c_]], 16, 0, 0); } while (0)

  STAGE_K(0, 0);

  for (int i = tid; i < 1024; i += 256) maskL2[i] = mask[b * 1024 + i] * L2E;

  // Q fragments: 32 rows (qg 0,1)
  bf16x8 qf[2][2];
  #pragma unroll
  for (int qg = 0; qg < 2; ++qg) {
    const u16* Qp = Q + ((size_t)bh * 1024 + qb + qg * 16 + lq) * 64 + g * 8;
    qf[qg][0] = *(const bf16x8*)Qp;
    qf[qg][1] = *(const bf16x8*)(Qp + 32);
  }

  // ---- hoisted LDS read offsets (lane-constant) ----
  int kOff[2][2];
  #pragma unroll
  for (int c = 0; c < 2; ++c) {
    int row128 = w * 32 + ((lq >> 2) << 3) + c * 4 + (lq & 3);   // kappa(A-row = lq)
    int F = (row128 & 3) | ((((row128 >> 3) ^ (row128 >> 4)) & 1) << 2);
    kOff[c][0] = row128 * 64 + ((g ^ F) * 8);
    kOff[c][1] = row128 * 64 + (((g + 4) ^ F) * 8);
  }
  int vOff[4];
  #pragma unroll
  for (int dc = 0; dc < 4; ++dc) {
    int row = dc * 16 + lq;
    vOff[dc] = row * 128 + (((w * 4 + g) ^ (row & 15)) * 8);
  }
  int mBase = w * 32 + g * 8;   // mask index = t*128 + mBase + c*4

  __syncthreads();   // K0 staged + maskL2 ready

  // ---- pass A: swapped QK^T (quarter x 32q), plain Z1 (max-free); scores discarded ----
  const float sl2e = 0.125f * L2E;
  float z1[2] = {0.f, 0.f};
  int cur = 0;
  #pragma unroll
  for (int t = 0; t < 8; ++t) {
    if (t < 7) STAGE_K(cur ^ 1, t + 1);
    else       STAGE_K(0, 0);            // prefetch pass-B K tile 0 (KVl[0] dead: cur==1 at t=7)
    #pragma unroll
    for (int c = 0; c < 2; ++c) {
      bf16x8 kf0 = *(const bf16x8*)&KVl[cur][kOff[c][0]];
      bf16x8 kf1 = *(const bf16x8*)&KVl[cur][kOff[c][1]];
      const float4 mk = *(const float4*)&maskL2[t * 128 + mBase + c * 4];
      #pragma unroll
      for (int qg = 0; qg < 2; ++qg) {
        f32x4 tt = {0.f, 0.f, 0.f, 0.f};
        tt = __builtin_amdgcn_mfma_f32_16x16x32_bf16(kf0, qf[qg][0], tt, 0, 0, 0);
        tt = __builtin_amdgcn_mfma_f32_16x16x32_bf16(kf1, qf[qg][1], tt, 0, 0, 0);
        float e0 = __builtin_amdgcn_exp2f(fmaf(tt[0], sl2e, mk.x));
        float e1 = __builtin_amdgcn_exp2f(fmaf(tt[1], sl2e, mk.y));
        float e2 = __builtin_amdgcn_exp2f(fmaf(tt[2], sl2e, mk.z));
        float e3 = __builtin_amdgcn_exp2f(fmaf(tt[3], sl2e, mk.w));
        z1[qg] += (e0 + e1) + (e2 + e3);
      }
    }
    __syncthreads();
    cur ^= 1;
  }
  // KVl[1] dead (t=7 read it, barrier passed) -> prefetch pass-B V tile 0
  STAGE_V(1, 0);

  // ---- merge Z1: g-groups (shfl) + 4 waves (LDS) -> lm[qg] = log2(Z1) ----
  #pragma unroll
  for (int qg = 0; qg < 2; ++qg) {
    z1[qg] += __shfl_xor(z1[qg], 16);
    z1[qg] += __shfl_xor(z1[qg], 32);
  }
  if (l < 16) { z1p[w][l] = z1[0]; z1p[w][16 + l] = z1[1]; }
  __syncthreads();
  float lm[2];
  #pragma unroll
  for (int qg = 0; qg < 2; ++qg) {
    int q = qg * 16 + lq;
    lm[qg] = __builtin_amdgcn_logf(((z1p[0][q] + z1p[1][q]) + (z1p[2][q] + z1p[3][q])));  // v_log_f32 = log2
  }

  // ---- pass B: recompute QK^T, p1 = exp2(s-lm), p2 = exp2(mkl - L2E*p1), PV ----
  f32x4 acc[2][4] = {};
  float z2[2] = {0.f, 0.f};
  #pragma unroll
  for (int t = 0; t < 8; ++t) {
    u32x4 pk[2];
    #pragma unroll
    for (int c = 0; c < 2; ++c) {
      bf16x8 kf0 = *(const bf16x8*)&KVl[0][kOff[c][0]];
      bf16x8 kf1 = *(const bf16x8*)&KVl[0][kOff[c][1]];
      const float4 mk = *(const float4*)&maskL2[t * 128 + mBase + c * 4];
      #pragma unroll
      for (int qg = 0; qg < 2; ++qg) {
        f32x4 tt = {0.f, 0.f, 0.f, 0.f};
        tt = __builtin_amdgcn_mfma_f32_16x16x32_bf16(kf0, qf[qg][0], tt, 0, 0, 0);
        tt = __builtin_amdgcn_mfma_f32_16x16x32_bf16(kf1, qf[qg][1], tt, 0, 0, 0);
        float p10 = __builtin_amdgcn_exp2f(fmaf(tt[0], sl2e, mk.x) - lm[qg]);
        float p11 = __builtin_amdgcn_exp2f(fmaf(tt[1], sl2e, mk.y) - lm[qg]);
        float p12 = __builtin_amdgcn_exp2f(fmaf(tt[2], sl2e, mk.z) - lm[qg]);
        float p13 = __builtin_amdgcn_exp2f(fmaf(tt[3], sl2e, mk.w) - lm[qg]);
        if (cl) {
          float p20 = __builtin_amdgcn_exp2f(fmaf(-L2E, p10, mk.x));
          float p21 = __builtin_amdgcn_exp2f(fmaf(-L2E, p11, mk.y));
          float p22 = __builtin_amdgcn_exp2f(fmaf(-L2E, p12, mk.z));
          float p23 = __builtin_amdgcn_exp2f(fmaf(-L2E, p13, mk.w));
          z2[qg] += (p20 + p21) + (p22 + p23);
          pk[qg][c * 2 + 0] = cvtpk(p20, p21);
          pk[qg][c * 2 + 1] = cvtpk(p22, p23);
        } else {
          pk[qg][c * 2 + 0] = cvtpk(p10, p11);   // normalized probs1 -> epilogue scale = 1
          pk[qg][c * 2 + 1] = cvtpk(p12, p13);
        }
      }
    }
    #pragma unroll
    for (int dc = 0; dc < 4; ++dc) {
      bf16x8 vf = *(const bf16x8*)&KVl[1][vOff[dc]];
      #pragma unroll
      for (int qg = 0; qg < 2; ++qg)
        acc[qg][dc] = __builtin_amdgcn_mfma_f32_16x16x32_bf16(
            __builtin_bit_cast(bf16x8, pk[qg]), vf, acc[qg][dc], 0, 0, 0);
    }
    __syncthreads();                       // all reads of tile t done
    if (t < 7) {
      STAGE_K(0, t + 1);
      STAGE_V(1, t + 1);
      __syncthreads();                     // tile t+1 landed + visible
    }
  }

  // ---- epilogue: 4-way Z2 merge + 4-way acc reduction through dead KVl ----
  #pragma unroll
  for (int qg = 0; qg < 2; ++qg) {
    z2[qg] += __shfl_xor(z2[qg], 16);
    z2[qg] += __shfl_xor(z2[qg], 32);
  }
  if (l < 16) { z2p[w][l] = z2[0]; z2p[w][16 + l] = z2[1]; }
  float* redF = (float*)&KVl[0][0];    // [3][32 q][68 d-stride] = 26112 B <= 32 KB
  if (w > 0) {
    #pragma unroll
    for (int qg = 0; qg < 2; ++qg)
      #pragma unroll
      for (int dc = 0; dc < 4; ++dc)
        #pragma unroll
        for (int r = 0; r < 4; ++r)
          redF[(w - 1) * 2176 + (qg * 16 + g * 4 + r) * 68 + dc * 16 + lq] = acc[qg][dc][r];
  }
  __syncthreads();
  if (w == 0) {
    #pragma unroll
    for (int qg = 0; qg < 2; ++qg) {
      #pragma unroll
      for (int r = 0; r < 4; ++r) {
        int q = qg * 16 + g * 4 + r;
        float Z2 = (z2p[0][q] + z2p[1][q]) + (z2p[2][q] + z2p[3][q]);
        float phi = cl ? __builtin_amdgcn_rcpf(Z2) : 1.0f;
        size_t orow = ((size_t)(b * 1024 + qb + q)) * 1024 + h * 64;
        #pragma unroll
        for (int dc = 0; dc < 4; ++dc) {
          int dq = q * 68 + dc * 16 + lq;
          float o = acc[qg][dc][r] + redF[dq] + redF[2176 + dq] + redF[4352 + dq];
          out[orow + dc * 16 + lq] = o * phi;
        }
      }
    }
  }
#undef STAGE_K
#undef STAGE_V
}

extern "C" void kernel_launch(void* const* d_in, const int* in_sizes, int n_in,
                              void* d_out, int out_size, void* d_ws, size_t ws_size,
                              hipStream_t stream) {
  const float* s1   = (const float*)d_in[0];
  const float* s2   = (const float*)d_in[1];
  const float* mask = (const float*)d_in[2];
  const float* Wq   = (const float*)d_in[3];
  const float* bq   = (const float*)d_in[4];
  const float* Wk   = (const float*)d_in[5];
  const float* bk   = (const float*)d_in[6];
  const float* Wv   = (const float*)d_in[7];
  const float* bv   = (const float*)d_in[8];
  const int*   cl   = (const int*)d_in[9];
  float* out = (float*)d_out;

  // ws layout (u16 elements): X1[8M] X2[8M] Wtq[1M] Wtk[1M] Wtv[1M] Q[8M] K[8M] Vt[8M]
  u16* ws  = (u16*)d_ws;
  const size_t M1 = 1024 * 1024;
  u16* X1  = ws;
  u16* X2  = ws + 8 * M1;
  u16* Wtq = ws + 16 * M1;
  u16* Wtk = Wtq + M1;
  u16* Wtv = Wtk + M1;
  u16* Qb  = Wtv + M1;
  u16* Kb  = Qb + 8 * M1;
  u16* Vtb = Kb + 8 * M1;   // V^T written directly by qkv_gemm3 (z==2)

  conv_f32_bf16<<<2048, 256, 0, stream>>>(s1, X1, 2097152);
  conv_f32_bf16<<<2048, 256, 0, stream>>>(s2, X2, 2097152);
  wtrans3<<<dim3(32, 32, 3), dim3(32, 8), 0, stream>>>(Wq, Wk, Wv, Wtq, Wtk, Wtv);
  qkv_gemm3<<<dim3(8, 64, 3), 256, 0, stream>>>(X1, X2, Wtq, Wtk, Wtv, bq, bk, bv, Qb, Kb, Vtb);
  attn12<<<4096, 256, 0, stream>>>(Qb, Kb, Vtb, mask, cl, out);
}

// Round 12
// 187.471 us; speedup vs baseline: 1.9504x; 1.1341x over previous
//
#include <hip/hip_runtime.h>
#include <hip/hip_bf16.h>

typedef unsigned short u16;
typedef __attribute__((ext_vector_type(8))) short bf16x8;   // 8 bf16 = 4 VGPRs (MFMA A/B frag)
typedef __attribute__((ext_vector_type(4))) float f32x4;    // MFMA C/D frag
typedef __attribute__((ext_vector_type(4))) unsigned u32x4;

#define L2E 1.4426950408889634f

__device__ __forceinline__ u16 f2bf(float f) {
  unsigned u = __float_as_uint(f);
  u = u + 0x7fffu + ((u >> 16) & 1u);   // RNE
  return (u16)(u >> 16);
}
__device__ __forceinline__ unsigned cvtpk(float a, float b) {  // low = bf16(a), high = bf16(b), HW RNE
  unsigned r;
  asm("v_cvt_pk_bf16_f32 %0, %1, %2" : "=v"(r) : "v"(a), "v"(b));
  return r;
}
__device__ __forceinline__ float lo16(unsigned v) { return __uint_as_float(v << 16); }
__device__ __forceinline__ float hi16(unsigned v) { return __uint_as_float(v & 0xffff0000u); }

// ---------------- prep: f32 -> bf16 elementwise ----------------
__global__ void conv_f32_bf16(const float* __restrict__ in, u16* __restrict__ out, int n4) {
  int i = blockIdx.x * blockDim.x + threadIdx.x;
  int stride = gridDim.x * blockDim.x;
  for (; i < n4; i += stride) {
    float4 v = ((const float4*)in)[i];
    ushort4 o = make_ushort4(f2bf(v.x), f2bf(v.y), f2bf(v.z), f2bf(v.w));
    ((ushort4*)out)[i] = o;
  }
}

// ---------------- prep: W[k][n] f32 -> Wt[n][k] bf16 (3 weights via blockIdx.z) ----------------
__global__ void wtrans3(const float* __restrict__ Wq, const float* __restrict__ Wk,
                        const float* __restrict__ Wv,
                        u16* __restrict__ Wtq, u16* __restrict__ Wtk, u16* __restrict__ Wtv) {
  int z = blockIdx.z;
  const float* W = (z == 0) ? Wq : (z == 1) ? Wk : Wv;
  u16* Wt = (z == 0) ? Wtq : (z == 1) ? Wtk : Wtv;
  __shared__ float T[32][33];
  int k0 = blockIdx.y * 32, n0 = blockIdx.x * 32;
  int tx = threadIdx.x, ty = threadIdx.y;       // (32,8)
  #pragma unroll
  for (int j = 0; j < 4; ++j) T[ty + 8*j][tx] = W[(size_t)(k0 + ty + 8*j) * 1024 + n0 + tx];
  __syncthreads();
  #pragma unroll
  for (int j = 0; j < 4; ++j) Wt[(size_t)(n0 + ty + 8*j) * 1024 + k0 + tx] = f2bf(T[tx][ty + 8*j]);
}

// ---------------- QKV projection GEMM (3 fused via blockIdx.z), global_load_lds staging ----------------
// z==2 (V projection) writes V^T [B,H,64,S] directly.
__global__ __launch_bounds__(256) void qkv_gemm3(const u16* __restrict__ X1, const u16* __restrict__ X2,
                                                 const u16* __restrict__ Wtq, const u16* __restrict__ Wtk,
                                                 const u16* __restrict__ Wtv,
                                                 const float* __restrict__ bq, const float* __restrict__ bk,
                                                 const float* __restrict__ bv,
                                                 u16* __restrict__ Qo, u16* __restrict__ Ko, u16* __restrict__ Vo) {
  int z = blockIdx.z;
  const u16* X   = (z == 0) ? X1 : X2;
  const u16* Wt  = (z == 0) ? Wtq : (z == 1) ? Wtk : Wtv;
  const float* bias = (z == 0) ? bq : (z == 1) ? bk : bv;
  u16* outp = (z == 0) ? Qo : (z == 1) ? Ko : Vo;

  __shared__ __align__(16) u16 As[128 * 32];
  __shared__ __align__(16) u16 Bs[128 * 32];
  int tid = threadIdx.x;
  int m0 = blockIdx.y * 128, n0 = blockIdx.x * 128;
  int w = tid >> 6, l = tid & 63;
  int wm = w >> 1, wn = w & 1;
  const int4* Xs = (const int4*)X;
  const int4* Ws = (const int4*)Wt;
  int4* As4 = (int4*)As;
  int4* Bs4 = (int4*)Bs;
  f32x4 acc[4][4] = {};
  for (int kt = 0; kt < 32; ++kt) {
    #pragma unroll
    for (int c = 0; c < 2; ++c) {
      int i = c * 256 + tid;              // 0..511 int4 chunks; dest = wave-uniform base + lane*16
      int row = i >> 2, kc = i & 3;
      __builtin_amdgcn_global_load_lds(
          (const __attribute__((address_space(1))) void*)&Xs[(size_t)(m0 + row) * 128 + kt * 4 + kc],
          (__attribute__((address_space(3))) void*)&As4[i], 16, 0, 0);
      __builtin_amdgcn_global_load_lds(
          (const __attribute__((address_space(1))) void*)&Ws[(size_t)(n0 + row) * 128 + kt * 4 + kc],
          (__attribute__((address_space(3))) void*)&Bs4[i], 16, 0, 0);
    }
    __syncthreads();
    bf16x8 a[4], bb[4];
    #pragma unroll
    for (int mc = 0; mc < 4; ++mc) a[mc]  = *(const bf16x8*)&As[(wm*64 + mc*16 + (l & 15)) * 32 + (l >> 4) * 8];
    #pragma unroll
    for (int nc = 0; nc < 4; ++nc) bb[nc] = *(const bf16x8*)&Bs[(wn*64 + nc*16 + (l & 15)) * 32 + (l >> 4) * 8];
    #pragma unroll
    for (int mc = 0; mc < 4; ++mc)
      #pragma unroll
      for (int nc = 0; nc < 4; ++nc)
        acc[mc][nc] = __builtin_amdgcn_mfma_f32_16x16x32_bf16(a[mc], bb[nc], acc[mc][nc], 0, 0, 0);
    __syncthreads();
  }
  #pragma unroll
  for (int nc = 0; nc < 4; ++nc) {
    int n = n0 + wn * 64 + nc * 16 + (l & 15);
    float bvv = bias[n];
    int h = n >> 6, d = n & 63;
    #pragma unroll
    for (int mc = 0; mc < 4; ++mc) {
      int srow_base = m0 + wm * 64 + mc * 16 + (l >> 4) * 4;
      if (z == 2) {
        int b = srow_base >> 10, s = srow_base & 1023;   // srow_base % 4 == 0, no b-crossing in r
        ushort4 vv;
        vv.x = f2bf(acc[mc][nc][0] + bvv);
        vv.y = f2bf(acc[mc][nc][1] + bvv);
        vv.z = f2bf(acc[mc][nc][2] + bvv);
        vv.w = f2bf(acc[mc][nc][3] + bvv);
        *(ushort4*)&outp[((size_t)((b * 16 + h) * 64 + d)) * 1024 + s] = vv;
      } else {
        #pragma unroll
        for (int r = 0; r < 4; ++r) {
          int sm = srow_base + r;
          int b = sm >> 10, s = sm & 1023;
          outp[((size_t)((b * 16 + h) * 1024 + s)) * 64 + d] = f2bf(acc[mc][nc][r] + bvv);
        }
      }
    }
  }
}

// ---------------- fused double-softmax attention, v13 ----------------
// v12 wave decomposition (wave = key-quarter, all 32 q-rows) but E STORED, not
// recomputed: pass A packs E = exp2(s + mkl) as bf16 into sp[64] (cvt_pk; the
// kappa-permutation makes sp exactly the PV A-fragments); pass B = unpack,
// p2 = exp2(mkl - cr*E), PV only — no K re-staging, no QK^T recompute.
// Freed KVl[0] -> pass-B V double-buffer, single barrier per tile (8 vs 16).
// grid 4096 = 8 xcd x 16 bh x 32 qt; 4 waves; LDS ~37KB.
__global__ __launch_bounds__(256, 2) void attn13(const u16* __restrict__ Q, const u16* __restrict__ K,
                                                 const u16* __restrict__ Vt, const float* __restrict__ mask,
                                                 const int* __restrict__ clp, float* __restrict__ out) {
  __shared__ __align__(16) u16 KVl[2][8192];   // pass A: K dbuf; pass B: V dbuf; epilogue: redF
  __shared__ __align__(16) float maskL2[1024]; // mask * log2e
  __shared__ float z1p[4][32];
  __shared__ float z2p[4][32];

  int bid = blockIdx.x;
  int xcd = bid & 7, idx = bid >> 3;
  int bh = xcd * 16 + (idx >> 5);   // 32 q-tile blocks share (b,h) within an XCD
  int qt = idx & 31;
  int b = bh >> 4, h = bh & 15;
  int tid = threadIdx.x;
  int w = tid >> 6, l = tid & 63;
  int lq = l & 15, g = l >> 4;
  int qb = qt * 32;

  const u16* Kb = K + (size_t)bh * 65536;
  const u16* Vb = Vt + (size_t)bh * 65536;
  int cl = clp[0];

  // ---- hoisted staging addresses (affine in t) ----
  const u16* kS[4]; int kD[4];
  #pragma unroll
  for (int c_ = 0; c_ < 4; ++c_) {
    int i_ = c_ * 256 + tid, row_ = i_ >> 3, ch_ = i_ & 7;
    int f_ = (row_ & 3) | ((((row_ >> 3) ^ (row_ >> 4)) & 1) << 2);
    kS[c_] = Kb + row_ * 64 + (ch_ ^ f_) * 8;
    kD[c_] = i_ * 8;
  }
  const u16* vS[4]; int vD[4];
  #pragma unroll
  for (int c_ = 0; c_ < 4; ++c_) {
    int i_ = c_ * 256 + tid, row_ = i_ >> 4, ch_ = i_ & 15;
    vS[c_] = Vb + row_ * 1024 + (ch_ ^ (row_ & 15)) * 8;
    vD[c_] = i_ * 8;
  }

#define STAGE_K(bi, t) do { _Pragma("unroll")                                                 \
    for (int c_ = 0; c_ < 4; ++c_)                                                           \
      __builtin_amdgcn_global_load_lds(                                                      \
        (const __attribute__((address_space(1))) void*)(kS[c_] + (t) * 8192),                \
        (__attribute__((address_space(3))) void*)&KVl[bi][kD[c_]], 16, 0, 0); } while (0)

#define STAGE_V(bi, t) do { _Pragma("unroll")                                                 \
    for (int c_ = 0; c_ < 4; ++c_)                                                           \
      __builtin_amdgcn_global_load_lds(                                                      \
        (const __attribute__((address_space(1))) void*)(vS[c_] + (t) * 128),                 \
        (__attribute__((address_space(3))) void*)&KVl[bi][vD[c_]], 16, 0, 0); } while (0)

  STAGE_K(0, 0);

  for (int i = tid; i < 1024; i += 256) maskL2[i] = mask[b * 1024 + i] * L2E;

  // Q fragments: 32 rows (qg 0,1)
  bf16x8 qf[2][2];
  #pragma unroll
  for (int qg = 0; qg < 2; ++qg) {
    const u16* Qp = Q + ((size_t)bh * 1024 + qb + qg * 16 + lq) * 64 + g * 8;
    qf[qg][0] = *(const bf16x8*)Qp;
    qf[qg][1] = *(const bf16x8*)(Qp + 32);
  }

  // ---- hoisted LDS read offsets (lane-constant) ----
  int kOff[2][2];
  #pragma unroll
  for (int c = 0; c < 2; ++c) {
    int row128 = w * 32 + ((lq >> 2) << 3) + c * 4 + (lq & 3);   // kappa(A-row = lq)
    int F = (row128 & 3) | ((((row128 >> 3) ^ (row128 >> 4)) & 1) << 2);
    kOff[c][0] = row128 * 64 + ((g ^ F) * 8);
    kOff[c][1] = row128 * 64 + (((g + 4) ^ F) * 8);
  }
  int vOff[4];
  #pragma unroll
  for (int dc = 0; dc < 4; ++dc) {
    int row = dc * 16 + lq;
    vOff[dc] = row * 128 + (((w * 4 + g) ^ (row & 15)) * 8);
  }
  int mBase = w * 32 + g * 8;   // mask index = t*128 + mBase + c*4

  __syncthreads();   // K0 staged + maskL2 ready

  // ---- pass A: swapped QK^T (quarter x 32q), E = exp2(s+mkl) packed to sp[64], Z1 ----
  const float sl2e = 0.125f * L2E;
  unsigned sp[64];
  float z1[2] = {0.f, 0.f};
  int cur = 0;
  #pragma unroll
  for (int t = 0; t < 8; ++t) {
    if (t < 7) STAGE_K(cur ^ 1, t + 1);
    else       STAGE_V(0, 0);            // prefetch pass-B V tile 0 (KVl[0] dead: cur==1 at t=7)
    #pragma unroll
    for (int c = 0; c < 2; ++c) {
      bf16x8 kf0 = *(const bf16x8*)&KVl[cur][kOff[c][0]];
      bf16x8 kf1 = *(const bf16x8*)&KVl[cur][kOff[c][1]];
      const float4 mk = *(const float4*)&maskL2[t * 128 + mBase + c * 4];
      #pragma unroll
      for (int qg = 0; qg < 2; ++qg) {
        f32x4 tt = {0.f, 0.f, 0.f, 0.f};
        tt = __builtin_amdgcn_mfma_f32_16x16x32_bf16(kf0, qf[qg][0], tt, 0, 0, 0);
        tt = __builtin_amdgcn_mfma_f32_16x16x32_bf16(kf1, qf[qg][1], tt, 0, 0, 0);
        float e0 = __builtin_amdgcn_exp2f(fmaf(tt[0], sl2e, mk.x));
        float e1 = __builtin_amdgcn_exp2f(fmaf(tt[1], sl2e, mk.y));
        float e2 = __builtin_amdgcn_exp2f(fmaf(tt[2], sl2e, mk.z));
        float e3 = __builtin_amdgcn_exp2f(fmaf(tt[3], sl2e, mk.w));
        z1[qg] += (e0 + e1) + (e2 + e3);
        sp[t * 8 + qg * 4 + c * 2 + 0] = cvtpk(e0, e1);
        sp[t * 8 + qg * 4 + c * 2 + 1] = cvtpk(e2, e3);
      }
    }
    __syncthreads();
    cur ^= 1;
  }

  // ---- merge Z1: g-groups (shfl) + 4 waves (LDS) -> cr[qg] = L2E / Z1 ----
  #pragma unroll
  for (int qg = 0; qg < 2; ++qg) {
    z1[qg] += __shfl_xor(z1[qg], 16);
    z1[qg] += __shfl_xor(z1[qg], 32);
  }
  if (l < 16) { z1p[w][l] = z1[0]; z1p[w][16 + l] = z1[1]; }
  __syncthreads();
  float cr[2];
  #pragma unroll
  for (int qg = 0; qg < 2; ++qg) {
    int q = qg * 16 + lq;
    float Z1 = (z1p[0][q] + z1p[1][q]) + (z1p[2][q] + z1p[3][q]);
    cr[qg] = L2E * __builtin_amdgcn_rcpf(Z1);
  }

  // ---- pass B: p2 = exp2(mkl - cr*E), PV over V dbuf (tile t in KVl[t&1]) ----
  f32x4 acc[2][4] = {};
  float z2[2] = {0.f, 0.f};
  #pragma unroll
  for (int t = 0; t < 8; ++t) {
    if (t < 7) STAGE_V((t + 1) & 1, t + 1);
    u32x4 pk[2];
    #pragma unroll
    for (int qg = 0; qg < 2; ++qg) {
      if (cl) {
        #pragma unroll
        for (int j = 0; j < 4; ++j) {
          unsigned e = sp[t * 8 + qg * 4 + j];
          float mkA = maskL2[t * 128 + mBase + 2 * j];
          float mkB = maskL2[t * 128 + mBase + 2 * j + 1];
          float pA = __builtin_amdgcn_exp2f(fmaf(-cr[qg], lo16(e), mkA));
          float pB = __builtin_amdgcn_exp2f(fmaf(-cr[qg], hi16(e), mkB));
          z2[qg] += pA + pB;
          pk[qg][j] = cvtpk(pA, pB);
        }
      } else {
        pk[qg] = *(u32x4*)&sp[t * 8 + qg * 4];   // unnormalized E; epilogue scales by 1/Z1
      }
    }
    #pragma unroll
    for (int dc = 0; dc < 4; ++dc) {
      bf16x8 vf = *(const bf16x8*)&KVl[t & 1][vOff[dc]];
      #pragma unroll
      for (int qg = 0; qg < 2; ++qg)
        acc[qg][dc] = __builtin_amdgcn_mfma_f32_16x16x32_bf16(
            __builtin_bit_cast(bf16x8, pk[qg]), vf, acc[qg][dc], 0, 0, 0);
    }
    if (t < 7) __syncthreads();            // tile t reads done + tile t+1 staged/visible
  }

  // ---- epilogue: 4-way Z2 merge + 4-way acc reduction through dead KVl ----
  #pragma unroll
  for (int qg = 0; qg < 2; ++qg) {
    z2[qg] += __shfl_xor(z2[qg], 16);
    z2[qg] += __shfl_xor(z2[qg], 32);
  }
  if (l < 16) { z2p[w][l] = z2[0]; z2p[w][16 + l] = z2[1]; }
  float* redF = (float*)&KVl[0][0];    // [3][32 q][68 d-stride] = 26112 B, KVl[0] dead since t=6 barrier
  if (w > 0) {
    #pragma unroll
    for (int qg = 0; qg < 2; ++qg)
      #pragma unroll
      for (int dc = 0; dc < 4; ++dc)
        #pragma unroll
        for (int r = 0; r < 4; ++r)
          redF[(w - 1) * 2176 + (qg * 16 + g * 4 + r) * 68 + dc * 16 + lq] = acc[qg][dc][r];
  }
  __syncthreads();
  if (w == 0) {
    #pragma unroll
    for (int qg = 0; qg < 2; ++qg) {
      #pragma unroll
      for (int r = 0; r < 4; ++r) {
        int q = qg * 16 + g * 4 + r;
        float phi;
        if (cl) {
          float Z2 = (z2p[0][q] + z2p[1][q]) + (z2p[2][q] + z2p[3][q]);
          phi = __builtin_amdgcn_rcpf(Z2);
        } else {
          float Z1 = (z1p[0][q] + z1p[1][q]) + (z1p[2][q] + z1p[3][q]);
          phi = __builtin_amdgcn_rcpf(Z1);
        }
        size_t orow = ((size_t)(b * 1024 + qb + q)) * 1024 + h * 64;
        #pragma unroll
        for (int dc = 0; dc < 4; ++dc) {
          int dq = q * 68 + dc * 16 + lq;
          float o = acc[qg][dc][r] + redF[dq] + redF[2176 + dq] + redF[4352 + dq];
          out[orow + dc * 16 + lq] = o * phi;
        }
      }
    }
  }
#undef STAGE_K
#undef STAGE_V
}

extern "C" void kernel_launch(void* const* d_in, const int* in_sizes, int n_in,
                              void* d_out, int out_size, void* d_ws, size_t ws_size,
                              hipStream_t stream) {
  const float* s1   = (const float*)d_in[0];
  const float* s2   = (const float*)d_in[1];
  const float* mask = (const float*)d_in[2];
  const float* Wq   = (const float*)d_in[3];
  const float* bq   = (const float*)d_in[4];
  const float* Wk   = (const float*)d_in[5];
  const float* bk   = (const float*)d_in[6];
  const float* Wv   = (const float*)d_in[7];
  const float* bv   = (const float*)d_in[8];
  const int*   cl   = (const int*)d_in[9];
  float* out = (float*)d_out;

  // ws layout (u16 elements): X1[8M] X2[8M] Wtq[1M] Wtk[1M] Wtv[1M] Q[8M] K[8M] Vt[8M]
  u16* ws  = (u16*)d_ws;
  const size_t M1 = 1024 * 1024;
  u16* X1  = ws;
  u16* X2  = ws + 8 * M1;
  u16* Wtq = ws + 16 * M1;
  u16* Wtk = Wtq + M1;
  u16* Wtv = Wtk + M1;
  u16* Qb  = Wtv + M1;
  u16* Kb  = Qb + 8 * M1;
  u16* Vtb = Kb + 8 * M1;   // V^T written directly by qkv_gemm3 (z==2)

  conv_f32_bf16<<<2048, 256, 0, stream>>>(s1, X1, 2097152);
  conv_f32_bf16<<<2048, 256, 0, stream>>>(s2, X2, 2097152);
  wtrans3<<<dim3(32, 32, 3), dim3(32, 8), 0, stream>>>(Wq, Wk, Wv, Wtq, Wtk, Wtv);
  qkv_gemm3<<<dim3(8, 64, 3), 256, 0, stream>>>(X1, X2, Wtq, Wtk, Wtv, bq, bk, bv, Qb, Kb, Vtb);
  attn13<<<4096, 256, 0, stream>>>(Qb, Kb, Vtb, mask, cl, out);
}

// Round 13
// 186.951 us; speedup vs baseline: 1.9559x; 1.0028x over previous
//
#include <hip/hip_runtime.h>
#include <hip/hip_bf16.h>

typedef unsigned short u16;
typedef __attribute__((ext_vector_type(8))) short bf16x8;   // 8 bf16 = 4 VGPRs (MFMA A/B frag)
typedef __attribute__((ext_vector_type(4))) float f32x4;    // MFMA C/D frag
typedef __attribute__((ext_vector_type(4))) unsigned u32x4;

#define L2E 1.4426950408889634f

__device__ __forceinline__ u16 f2bf(float f) {
  unsigned u = __float_as_uint(f);
  u = u + 0x7fffu + ((u >> 16) & 1u);   // RNE
  return (u16)(u >> 16);
}
__device__ __forceinline__ unsigned cvtpk(float a, float b) {  // low = bf16(a), high = bf16(b), HW RNE
  unsigned r;
  asm("v_cvt_pk_bf16_f32 %0, %1, %2" : "=v"(r) : "v"(a), "v"(b));
  return r;
}
__device__ __forceinline__ float lo16(unsigned v) { return __uint_as_float(v << 16); }
__device__ __forceinline__ float hi16(unsigned v) { return __uint_as_float(v & 0xffff0000u); }

// ---------------- prep: f32 -> bf16, both inputs in one launch ----------------
// X1/X2 are contiguous in ws, so output indexes linearly; input branches at n4a.
__global__ void conv2_f32_bf16(const float* __restrict__ a, const float* __restrict__ b,
                               u16* __restrict__ o, int n4a, int n4tot) {
  int i = blockIdx.x * blockDim.x + threadIdx.x;
  int stride = gridDim.x * blockDim.x;
  for (; i < n4tot; i += stride) {
    float4 v = (i < n4a) ? ((const float4*)a)[i] : ((const float4*)b)[i - n4a];
    ushort4 ov = make_ushort4(f2bf(v.x), f2bf(v.y), f2bf(v.z), f2bf(v.w));
    ((ushort4*)o)[i] = ov;
  }
}

// ---------------- prep: W[k][n] f32 -> Wt[n][k] bf16 (3 weights via blockIdx.z) ----------------
__global__ void wtrans3(const float* __restrict__ Wq, const float* __restrict__ Wk,
                        const float* __restrict__ Wv,
                        u16* __restrict__ Wtq, u16* __restrict__ Wtk, u16* __restrict__ Wtv) {
  int z = blockIdx.z;
  const float* W = (z == 0) ? Wq : (z == 1) ? Wk : Wv;
  u16* Wt = (z == 0) ? Wtq : (z == 1) ? Wtk : Wtv;
  __shared__ float T[32][33];
  int k0 = blockIdx.y * 32, n0 = blockIdx.x * 32;
  int tx = threadIdx.x, ty = threadIdx.y;       // (32,8)
  #pragma unroll
  for (int j = 0; j < 4; ++j) T[ty + 8*j][tx] = W[(size_t)(k0 + ty + 8*j) * 1024 + n0 + tx];
  __syncthreads();
  #pragma unroll
  for (int j = 0; j < 4; ++j) Wt[(size_t)(n0 + ty + 8*j) * 1024 + k0 + tx] = f2bf(T[tx][ty + 8*j]);
}

// ---------------- QKV projection GEMM (3 fused via blockIdx.z) ----------------
// T3-minimum double-buffered staging: STAGE(next) issued BEFORE compute(cur),
// single barrier per K-step (vmcnt drained by the barrier). z==2 writes V^T.
__global__ __launch_bounds__(256) void qkv_gemm3(const u16* __restrict__ X1, const u16* __restrict__ X2,
                                                 const u16* __restrict__ Wtq, const u16* __restrict__ Wtk,
                                                 const u16* __restrict__ Wtv,
                                                 const float* __restrict__ bq, const float* __restrict__ bk,
                                                 const float* __restrict__ bv,
                                                 u16* __restrict__ Qo, u16* __restrict__ Ko, u16* __restrict__ Vo) {
  int z = blockIdx.z;
  const u16* X   = (z == 0) ? X1 : X2;
  const u16* Wt  = (z == 0) ? Wtq : (z == 1) ? Wtk : Wtv;
  const float* bias = (z == 0) ? bq : (z == 1) ? bk : bv;
  u16* outp = (z == 0) ? Qo : (z == 1) ? Ko : Vo;

  __shared__ __align__(16) u16 As[2][128 * 32];
  __shared__ __align__(16) u16 Bs[2][128 * 32];
  int tid = threadIdx.x;
  int m0 = blockIdx.y * 128, n0 = blockIdx.x * 128;
  int w = tid >> 6, l = tid & 63;
  int wm = w >> 1, wn = w & 1;
  const int4* Xs = (const int4*)X;
  const int4* Ws = (const int4*)Wt;

#define QSTAGE(bi, kt) do { _Pragma("unroll")                                                \
    for (int c_ = 0; c_ < 2; ++c_) {                                                         \
      int i_ = c_ * 256 + tid;              /* 0..511 int4 chunks */                         \
      int row_ = i_ >> 2, kc_ = i_ & 3;                                                      \
      __builtin_amdgcn_global_load_lds(                                                      \
          (const __attribute__((address_space(1))) void*)&Xs[(size_t)(m0 + row_) * 128 + (kt) * 4 + kc_], \
          (__attribute__((address_space(3))) void*)&((int4*)As[bi])[i_], 16, 0, 0);          \
      __builtin_amdgcn_global_load_lds(                                                      \
          (const __attribute__((address_space(1))) void*)&Ws[(size_t)(n0 + row_) * 128 + (kt) * 4 + kc_], \
          (__attribute__((address_space(3))) void*)&((int4*)Bs[bi])[i_], 16, 0, 0);          \
    } } while (0)

  f32x4 acc[4][4] = {};
  QSTAGE(0, 0);
  __syncthreads();
  int cur = 0;
  for (int kt = 0; kt < 32; ++kt) {
    if (kt < 31) QSTAGE(cur ^ 1, kt + 1);   // overlap next-tile loads with compute
    bf16x8 a[4], bb[4];
    #pragma unroll
    for (int mc = 0; mc < 4; ++mc) a[mc]  = *(const bf16x8*)&As[cur][(wm*64 + mc*16 + (l & 15)) * 32 + (l >> 4) * 8];
    #pragma unroll
    for (int nc = 0; nc < 4; ++nc) bb[nc] = *(const bf16x8*)&Bs[cur][(wn*64 + nc*16 + (l & 15)) * 32 + (l >> 4) * 8];
    #pragma unroll
    for (int mc = 0; mc < 4; ++mc)
      #pragma unroll
      for (int nc = 0; nc < 4; ++nc)
        acc[mc][nc] = __builtin_amdgcn_mfma_f32_16x16x32_bf16(a[mc], bb[nc], acc[mc][nc], 0, 0, 0);
    __syncthreads();                        // drains vmcnt -> tile kt+1 visible; buffer cur free
    cur ^= 1;
  }
#undef QSTAGE
  #pragma unroll
  for (int nc = 0; nc < 4; ++nc) {
    int n = n0 + wn * 64 + nc * 16 + (l & 15);
    float bvv = bias[n];
    int h = n >> 6, d = n & 63;
    #pragma unroll
    for (int mc = 0; mc < 4; ++mc) {
      int srow_base = m0 + wm * 64 + mc * 16 + (l >> 4) * 4;
      if (z == 2) {
        int b = srow_base >> 10, s = srow_base & 1023;   // srow_base % 4 == 0, no b-crossing in r
        ushort4 vv;
        vv.x = f2bf(acc[mc][nc][0] + bvv);
        vv.y = f2bf(acc[mc][nc][1] + bvv);
        vv.z = f2bf(acc[mc][nc][2] + bvv);
        vv.w = f2bf(acc[mc][nc][3] + bvv);
        *(ushort4*)&outp[((size_t)((b * 16 + h) * 64 + d)) * 1024 + s] = vv;
      } else {
        #pragma unroll
        for (int r = 0; r < 4; ++r) {
          int sm = srow_base + r;
          int b = sm >> 10, s = sm & 1023;
          outp[((size_t)((b * 16 + h) * 1024 + s)) * 64 + d] = f2bf(acc[mc][nc][r] + bvv);
        }
      }
    }
  }
}

// ---------------- fused double-softmax attention, v13 (frozen from R12) ----------------
__global__ __launch_bounds__(256, 2) void attn13(const u16* __restrict__ Q, const u16* __restrict__ K,
                                                 const u16* __restrict__ Vt, const float* __restrict__ mask,
                                                 const int* __restrict__ clp, float* __restrict__ out) {
  __shared__ __align__(16) u16 KVl[2][8192];   // pass A: K dbuf; pass B: V dbuf; epilogue: redF
  __shared__ __align__(16) float maskL2[1024]; // mask * log2e
  __shared__ float z1p[4][32];
  __shared__ float z2p[4][32];

  int bid = blockIdx.x;
  int xcd = bid & 7, idx = bid >> 3;
  int bh = xcd * 16 + (idx >> 5);   // 32 q-tile blocks share (b,h) within an XCD
  int qt = idx & 31;
  int b = bh >> 4, h = bh & 15;
  int tid = threadIdx.x;
  int w = tid >> 6, l = tid & 63;
  int lq = l & 15, g = l >> 4;
  int qb = qt * 32;

  const u16* Kb = K + (size_t)bh * 65536;
  const u16* Vb = Vt + (size_t)bh * 65536;
  int cl = clp[0];

  // ---- hoisted staging addresses (affine in t) ----
  const u16* kS[4]; int kD[4];
  #pragma unroll
  for (int c_ = 0; c_ < 4; ++c_) {
    int i_ = c_ * 256 + tid, row_ = i_ >> 3, ch_ = i_ & 7;
    int f_ = (row_ & 3) | ((((row_ >> 3) ^ (row_ >> 4)) & 1) << 2);
    kS[c_] = Kb + row_ * 64 + (ch_ ^ f_) * 8;
    kD[c_] = i_ * 8;
  }
  const u16* vS[4]; int vD[4];
  #pragma unroll
  for (int c_ = 0; c_ < 4; ++c_) {
    int i_ = c_ * 256 + tid, row_ = i_ >> 4, ch_ = i_ & 15;
    vS[c_] = Vb + row_ * 1024 + (ch_ ^ (row_ & 15)) * 8;
    vD[c_] = i_ * 8;
  }

#define STAGE_K(bi, t) do { _Pragma("unroll")                                                 \
    for (int c_ = 0; c_ < 4; ++c_)                                                           \
      __builtin_amdgcn_global_load_lds(                                                      \
        (const __attribute__((address_space(1))) void*)(kS[c_] + (t) * 8192),                \
        (__attribute__((address_space(3))) void*)&KVl[bi][kD[c_]], 16, 0, 0); } while (0)

#define STAGE_V(bi, t) do { _Pragma("unroll")                                                 \
    for (int c_ = 0; c_ < 4; ++c_)                                                           \
      __builtin_amdgcn_global_load_lds(                                                      \
        (const __attribute__((address_space(1))) void*)(vS[c_] + (t) * 128),                 \
        (__attribute__((address_space(3))) void*)&KVl[bi][vD[c_]], 16, 0, 0); } while (0)

  STAGE_K(0, 0);

  for (int i = tid; i < 1024; i += 256) maskL2[i] = mask[b * 1024 + i] * L2E;

  // Q fragments: 32 rows (qg 0,1)
  bf16x8 qf[2][2];
  #pragma unroll
  for (int qg = 0; qg < 2; ++qg) {
    const u16* Qp = Q + ((size_t)bh * 1024 + qb + qg * 16 + lq) * 64 + g * 8;
    qf[qg][0] = *(const bf16x8*)Qp;
    qf[qg][1] = *(const bf16x8*)(Qp + 32);
  }

  // ---- hoisted LDS read offsets (lane-constant) ----
  int kOff[2][2];
  #pragma unroll
  for (int c = 0; c < 2; ++c) {
    int row128 = w * 32 + ((lq >> 2) << 3) + c * 4 + (lq & 3);   // kappa(A-row = lq)
    int F = (row128 & 3) | ((((row128 >> 3) ^ (row128 >> 4)) & 1) << 2);
    kOff[c][0] = row128 * 64 + ((g ^ F) * 8);
    kOff[c][1] = row128 * 64 + (((g + 4) ^ F) * 8);
  }
  int vOff[4];
  #pragma unroll
  for (int dc = 0; dc < 4; ++dc) {
    int row = dc * 16 + lq;
    vOff[dc] = row * 128 + (((w * 4 + g) ^ (row & 15)) * 8);
  }
  int mBase = w * 32 + g * 8;   // mask index = t*128 + mBase + c*4

  __syncthreads();   // K0 staged + maskL2 ready

  // ---- pass A: swapped QK^T (quarter x 32q), E = exp2(s+mkl) packed to sp[64], Z1 ----
  const float sl2e = 0.125f * L2E;
  unsigned sp[64];
  float z1[2] = {0.f, 0.f};
  int cur = 0;
  #pragma unroll
  for (int t = 0; t < 8; ++t) {
    if (t < 7) STAGE_K(cur ^ 1, t + 1);
    else       STAGE_V(0, 0);            // prefetch pass-B V tile 0 (KVl[0] dead: cur==1 at t=7)
    #pragma unroll
    for (int c = 0; c < 2; ++c) {
      bf16x8 kf0 = *(const bf16x8*)&KVl[cur][kOff[c][0]];
      bf16x8 kf1 = *(const bf16x8*)&KVl[cur][kOff[c][1]];
      const float4 mk = *(const float4*)&maskL2[t * 128 + mBase + c * 4];
      #pragma unroll
      for (int qg = 0; qg < 2; ++qg) {
        f32x4 tt = {0.f, 0.f, 0.f, 0.f};
        tt = __builtin_amdgcn_mfma_f32_16x16x32_bf16(kf0, qf[qg][0], tt, 0, 0, 0);
        tt = __builtin_amdgcn_mfma_f32_16x16x32_bf16(kf1, qf[qg][1], tt, 0, 0, 0);
        float e0 = __builtin_amdgcn_exp2f(fmaf(tt[0], sl2e, mk.x));
        float e1 = __builtin_amdgcn_exp2f(fmaf(tt[1], sl2e, mk.y));
        float e2 = __builtin_amdgcn_exp2f(fmaf(tt[2], sl2e, mk.z));
        float e3 = __builtin_amdgcn_exp2f(fmaf(tt[3], sl2e, mk.w));
        z1[qg] += (e0 + e1) + (e2 + e3);
        sp[t * 8 + qg * 4 + c * 2 + 0] = cvtpk(e0, e1);
        sp[t * 8 + qg * 4 + c * 2 + 1] = cvtpk(e2, e3);
      }
    }
    __syncthreads();
    cur ^= 1;
  }

  // ---- merge Z1: g-groups (shfl) + 4 waves (LDS) -> cr[qg] = L2E / Z1 ----
  #pragma unroll
  for (int qg = 0; qg < 2; ++qg) {
    z1[qg] += __shfl_xor(z1[qg], 16);
    z1[qg] += __shfl_xor(z1[qg], 32);
  }
  if (l < 16) { z1p[w][l] = z1[0]; z1p[w][16 + l] = z1[1]; }
  __syncthreads();
  float cr[2];
  #pragma unroll
  for (int qg = 0; qg < 2; ++qg) {
    int q = qg * 16 + lq;
    float Z1 = (z1p[0][q] + z1p[1][q]) + (z1p[2][q] + z1p[3][q]);
    cr[qg] = L2E * __builtin_amdgcn_rcpf(Z1);
  }

  // ---- pass B: p2 = exp2(mkl - cr*E), PV over V dbuf (tile t in KVl[t&1]) ----
  f32x4 acc[2][4] = {};
  float z2[2] = {0.f, 0.f};
  #pragma unroll
  for (int t = 0; t < 8; ++t) {
    if (t < 7) STAGE_V((t + 1) & 1, t + 1);
    u32x4 pk[2];
    #pragma unroll
    for (int qg = 0; qg < 2; ++qg) {
      if (cl) {
        #pragma unroll
        for (int j = 0; j < 4; ++j) {
          unsigned e = sp[t * 8 + qg * 4 + j];
          float mkA = maskL2[t * 128 + mBase + 2 * j];
          float mkB = maskL2[t * 128 + mBase + 2 * j + 1];
          float pA = __builtin_amdgcn_exp2f(fmaf(-cr[qg], lo16(e), mkA));
          float pB = __builtin_amdgcn_exp2f(fmaf(-cr[qg], hi16(e), mkB));
          z2[qg] += pA + pB;
          pk[qg][j] = cvtpk(pA, pB);
        }
      } else {
        pk[qg] = *(u32x4*)&sp[t * 8 + qg * 4];   // unnormalized E; epilogue scales by 1/Z1
      }
    }
    #pragma unroll
    for (int dc = 0; dc < 4; ++dc) {
      bf16x8 vf = *(const bf16x8*)&KVl[t & 1][vOff[dc]];
      #pragma unroll
      for (int qg = 0; qg < 2; ++qg)
        acc[qg][dc] = __builtin_amdgcn_mfma_f32_16x16x32_bf16(
            __builtin_bit_cast(bf16x8, pk[qg]), vf, acc[qg][dc], 0, 0, 0);
    }
    if (t < 7) __syncthreads();            // tile t reads done + tile t+1 staged/visible
  }

  // ---- epilogue: 4-way Z2 merge + 4-way acc reduction through dead KVl ----
  #pragma unroll
  for (int qg = 0; qg < 2; ++qg) {
    z2[qg] += __shfl_xor(z2[qg], 16);
    z2[qg] += __shfl_xor(z2[qg], 32);
  }
  if (l < 16) { z2p[w][l] = z2[0]; z2p[w][16 + l] = z2[1]; }
  float* redF = (float*)&KVl[0][0];    // [3][32 q][68 d-stride] = 26112 B, KVl[0] dead since t=6 barrier
  if (w > 0) {
    #pragma unroll
    for (int qg = 0; qg < 2; ++qg)
      #pragma unroll
      for (int dc = 0; dc < 4; ++dc)
        #pragma unroll
        for (int r = 0; r < 4; ++r)
          redF[(w - 1) * 2176 + (qg * 16 + g * 4 + r) * 68 + dc * 16 + lq] = acc[qg][dc][r];
  }
  __syncthreads();
  if (w == 0) {
    #pragma unroll
    for (int qg = 0; qg < 2; ++qg) {
      #pragma unroll
      for (int r = 0; r < 4; ++r) {
        int q = qg * 16 + g * 4 + r;
        float phi;
        if (cl) {
          float Z2 = (z2p[0][q] + z2p[1][q]) + (z2p[2][q] + z2p[3][q]);
          phi = __builtin_amdgcn_rcpf(Z2);
        } else {
          float Z1 = (z1p[0][q] + z1p[1][q]) + (z1p[2][q] + z1p[3][q]);
          phi = __builtin_amdgcn_rcpf(Z1);
        }
        size_t orow = ((size_t)(b * 1024 + qb + q)) * 1024 + h * 64;
        #pragma unroll
        for (int dc = 0; dc < 4; ++dc) {
          int dq = q * 68 + dc * 16 + lq;
          float o = acc[qg][dc][r] + redF[dq] + redF[2176 + dq] + redF[4352 + dq];
          out[orow + dc * 16 + lq] = o * phi;
        }
      }
    }
  }
#undef STAGE_K
#undef STAGE_V
}

extern "C" void kernel_launch(void* const* d_in, const int* in_sizes, int n_in,
                              void* d_out, int out_size, void* d_ws, size_t ws_size,
                              hipStream_t stream) {
  const float* s1   = (const float*)d_in[0];
  const float* s2   = (const float*)d_in[1];
  const float* mask = (const float*)d_in[2];
  const float* Wq   = (const float*)d_in[3];
  const float* bq   = (const float*)d_in[4];
  const float* Wk   = (const float*)d_in[5];
  const float* bk   = (const float*)d_in[6];
  const float* Wv   = (const float*)d_in[7];
  const float* bv   = (const float*)d_in[8];
  const int*   cl   = (const int*)d_in[9];
  float* out = (float*)d_out;

  // ws layout (u16 elements): X1[8M] X2[8M] Wtq[1M] Wtk[1M] Wtv[1M] Q[8M] K[8M] Vt[8M]
  u16* ws  = (u16*)d_ws;
  const size_t M1 = 1024 * 1024;
  u16* X1  = ws;                 // X2 = X1 + 8M (contiguous -> fused conv writes linearly)
  u16* Wtq = ws + 16 * M1;
  u16* Wtk = Wtq + M1;
  u16* Wtv = Wtk + M1;
  u16* Qb  = Wtv + M1;
  u16* Kb  = Qb + 8 * M1;
  u16* Vtb = Kb + 8 * M1;        // V^T written directly by qkv_gemm3 (z==2)
  u16* X2  = ws + 8 * M1;

  conv2_f32_bf16<<<2048, 256, 0, stream>>>(s1, s2, X1, 2097152, 4194304);
  wtrans3<<<dim3(32, 32, 3), dim3(32, 8), 0, stream>>>(Wq, Wk, Wv, Wtq, Wtk, Wtv);
  qkv_gemm3<<<dim3(8, 64, 3), 256, 0, stream>>>(X1, X2, Wtq, Wtk, Wtv, bq, bk, bv, Qb, Kb, Vtb);
  attn13<<<4096, 256, 0, stream>>>(Qb, Kb, Vtb, mask, cl, out);
}

// Round 14
// 177.209 us; speedup vs baseline: 2.0634x; 1.0550x over previous
//
#include <hip/hip_runtime.h>
#include <hip/hip_bf16.h>

typedef unsigned short u16;
typedef __attribute__((ext_vector_type(8))) short bf16x8;   // 8 bf16 = 4 VGPRs (MFMA A/B frag)
typedef __attribute__((ext_vector_type(4))) float f32x4;    // MFMA C/D frag
typedef __attribute__((ext_vector_type(4))) unsigned u32x4;

#define L2E 1.4426950408889634f

__device__ __forceinline__ u16 f2bf(float f) {
  unsigned u = __float_as_uint(f);
  u = u + 0x7fffu + ((u >> 16) & 1u);   // RNE
  return (u16)(u >> 16);
}
__device__ __forceinline__ unsigned cvtpk(float a, float b) {  // low = bf16(a), high = bf16(b), HW RNE
  unsigned r;
  asm("v_cvt_pk_bf16_f32 %0, %1, %2" : "=v"(r) : "v"(a), "v"(b));
  return r;
}
__device__ __forceinline__ float lo16(unsigned v) { return __uint_as_float(v << 16); }
__device__ __forceinline__ float hi16(unsigned v) { return __uint_as_float(v & 0xffff0000u); }

// ---------------- prep: f32 -> bf16, both inputs in one launch ----------------
__global__ void conv2_f32_bf16(const float* __restrict__ a, const float* __restrict__ b,
                               u16* __restrict__ o, int n4a, int n4tot) {
  int i = blockIdx.x * blockDim.x + threadIdx.x;
  int stride = gridDim.x * blockDim.x;
  for (; i < n4tot; i += stride) {
    float4 v = (i < n4a) ? ((const float4*)a)[i] : ((const float4*)b)[i - n4a];
    ushort4 ov = make_ushort4(f2bf(v.x), f2bf(v.y), f2bf(v.z), f2bf(v.w));
    ((ushort4*)o)[i] = ov;
  }
}

// ---------------- prep: W[k][n] f32 -> Wt[n][k] bf16 (3 weights via blockIdx.z) ----------------
__global__ void wtrans3(const float* __restrict__ Wq, const float* __restrict__ Wk,
                        const float* __restrict__ Wv,
                        u16* __restrict__ Wtq, u16* __restrict__ Wtk, u16* __restrict__ Wtv) {
  int z = blockIdx.z;
  const float* W = (z == 0) ? Wq : (z == 1) ? Wk : Wv;
  u16* Wt = (z == 0) ? Wtq : (z == 1) ? Wtk : Wtv;
  __shared__ float T[32][33];
  int k0 = blockIdx.y * 32, n0 = blockIdx.x * 32;
  int tx = threadIdx.x, ty = threadIdx.y;       // (32,8)
  #pragma unroll
  for (int j = 0; j < 4; ++j) T[ty + 8*j][tx] = W[(size_t)(k0 + ty + 8*j) * 1024 + n0 + tx];
  __syncthreads();
  #pragma unroll
  for (int j = 0; j < 4; ++j) Wt[(size_t)(n0 + ty + 8*j) * 1024 + k0 + tx] = f2bf(T[tx][ty + 8*j]);
}

// ---------------- QKV projection GEMM (1D grid, XCD-aware decode) ----------------
// grid 1536 = 8 xcd x 24 (z,y)-pairs x 8 n-blocks: the 8 n-blocks sharing an
// X row-panel land on ONE XCD's L2 (attn's verified bid&7 pattern) -> each X
// panel fetched from HBM once. LDS tiles chunk-swizzled (linear dest +
// inverse-swizzled source + swizzled read, F=(row>>1)&3) -> 2-way banks (free).
// T3-minimum dbuf staging; z==2 writes V^T.
__global__ __launch_bounds__(256) void qkv_gemm3(const u16* __restrict__ X1, const u16* __restrict__ X2,
                                                 const u16* __restrict__ Wtq, const u16* __restrict__ Wtk,
                                                 const u16* __restrict__ Wtv,
                                                 const float* __restrict__ bq, const float* __restrict__ bk,
                                                 const float* __restrict__ bv,
                                                 u16* __restrict__ Qo, u16* __restrict__ Ko, u16* __restrict__ Vo) {
  int bid = blockIdx.x;
  int xcd = bid & 7, idx = bid >> 3;
  int nblk = idx & 7, pair = idx >> 3;
  int zy = xcd * 24 + pair;          // [0,192): 24 (z,y) pairs per XCD
  int z = zy >> 6, y = zy & 63;
  int m0 = y * 128, n0 = nblk * 128;

  const u16* X   = (z == 0) ? X1 : X2;
  const u16* Wt  = (z == 0) ? Wtq : (z == 1) ? Wtk : Wtv;
  const float* bias = (z == 0) ? bq : (z == 1) ? bk : bv;
  u16* outp = (z == 0) ? Qo : (z == 1) ? Ko : Vo;

  __shared__ __align__(16) u16 As[2][128 * 32];
  __shared__ __align__(16) u16 Bs[2][128 * 32];
  int tid = threadIdx.x;
  int w = tid >> 6, l = tid & 63;
  int wm = w >> 1, wn = w & 1;
  int lq = l & 15, g = l >> 4;
  const int4* Xs = (const int4*)X;
  const int4* Ws = (const int4*)Wt;

  // staging: dest chunk i=(row, ch of 4); src k-chunk = ch ^ F(row), F=(row>>1)&3
#define QSTAGE(bi, kt) do { _Pragma("unroll")                                                \
    for (int c_ = 0; c_ < 2; ++c_) {                                                        \
      int i_ = c_ * 256 + tid;              /* 0..511 int4 chunks */                        \
      int row_ = i_ >> 2, kc_ = (i_ & 3) ^ ((row_ >> 1) & 3);                               \
      __builtin_amdgcn_global_load_lds(                                                     \
          (const __attribute__((address_space(1))) void*)&Xs[(size_t)(m0 + row_) * 128 + (kt) * 4 + kc_], \
          (__attribute__((address_space(3))) void*)&((int4*)As[bi])[i_], 16, 0, 0);         \
      __builtin_amdgcn_global_load_lds(                                                     \
          (const __attribute__((address_space(1))) void*)&Ws[(size_t)(n0 + row_) * 128 + (kt) * 4 + kc_], \
          (__attribute__((address_space(3))) void*)&((int4*)Bs[bi])[i_], 16, 0, 0);         \
    } } while (0)

  // hoisted swizzled read offsets (loop-invariant): row's global chunk g lives at LDS chunk g^F(row)
  int aOff[4], bOff[4];
  #pragma unroll
  for (int mc = 0; mc < 4; ++mc) {
    int rowA = wm * 64 + mc * 16 + lq;
    aOff[mc] = rowA * 32 + ((g ^ ((rowA >> 1) & 3)) * 8);
    int rowB = wn * 64 + mc * 16 + lq;
    bOff[mc] = rowB * 32 + ((g ^ ((rowB >> 1) & 3)) * 8);
  }

  f32x4 acc[4][4] = {};
  QSTAGE(0, 0);
  __syncthreads();
  int cur = 0;
  for (int kt = 0; kt < 32; ++kt) {
    if (kt < 31) QSTAGE(cur ^ 1, kt + 1);   // overlap next-tile loads with compute
    bf16x8 a[4], bb[4];
    #pragma unroll
    for (int mc = 0; mc < 4; ++mc) a[mc]  = *(const bf16x8*)&As[cur][aOff[mc]];
    #pragma unroll
    for (int nc = 0; nc < 4; ++nc) bb[nc] = *(const bf16x8*)&Bs[cur][bOff[nc]];
    #pragma unroll
    for (int mc = 0; mc < 4; ++mc)
      #pragma unroll
      for (int nc = 0; nc < 4; ++nc)
        acc[mc][nc] = __builtin_amdgcn_mfma_f32_16x16x32_bf16(a[mc], bb[nc], acc[mc][nc], 0, 0, 0);
    __syncthreads();                        // drains vmcnt -> tile kt+1 visible; buffer cur free
    cur ^= 1;
  }
#undef QSTAGE
  #pragma unroll
  for (int nc = 0; nc < 4; ++nc) {
    int n = n0 + wn * 64 + nc * 16 + lq;
    float bvv = bias[n];
    int h = n >> 6, d = n & 63;
    #pragma unroll
    for (int mc = 0; mc < 4; ++mc) {
      int srow_base = m0 + wm * 64 + mc * 16 + g * 4;
      if (z == 2) {
        int b = srow_base >> 10, s = srow_base & 1023;   // srow_base % 4 == 0, no b-crossing in r
        ushort4 vv;
        vv.x = f2bf(acc[mc][nc][0] + bvv);
        vv.y = f2bf(acc[mc][nc][1] + bvv);
        vv.z = f2bf(acc[mc][nc][2] + bvv);
        vv.w = f2bf(acc[mc][nc][3] + bvv);
        *(ushort4*)&outp[((size_t)((b * 16 + h) * 64 + d)) * 1024 + s] = vv;
      } else {
        #pragma unroll
        for (int r = 0; r < 4; ++r) {
          int sm = srow_base + r;
          int b = sm >> 10, s = sm & 1023;
          outp[((size_t)((b * 16 + h) * 1024 + s)) * 64 + d] = f2bf(acc[mc][nc][r] + bvv);
        }
      }
    }
  }
}

// ---------------- fused double-softmax attention, v13 (frozen from R12) ----------------
__global__ __launch_bounds__(256, 2) void attn13(const u16* __restrict__ Q, const u16* __restrict__ K,
                                                 const u16* __restrict__ Vt, const float* __restrict__ mask,
                                                 const int* __restrict__ clp, float* __restrict__ out) {
  __shared__ __align__(16) u16 KVl[2][8192];   // pass A: K dbuf; pass B: V dbuf; epilogue: redF
  __shared__ __align__(16) float maskL2[1024]; // mask * log2e
  __shared__ float z1p[4][32];
  __shared__ float z2p[4][32];

  int bid = blockIdx.x;
  int xcd = bid & 7, idx = bid >> 3;
  int bh = xcd * 16 + (idx >> 5);   // 32 q-tile blocks share (b,h) within an XCD
  int qt = idx & 31;
  int b = bh >> 4, h = bh & 15;
  int tid = threadIdx.x;
  int w = tid >> 6, l = tid & 63;
  int lq = l & 15, g = l >> 4;
  int qb = qt * 32;

  const u16* Kb = K + (size_t)bh * 65536;
  const u16* Vb = Vt + (size_t)bh * 65536;
  int cl = clp[0];

  // ---- hoisted staging addresses (affine in t) ----
  const u16* kS[4]; int kD[4];
  #pragma unroll
  for (int c_ = 0; c_ < 4; ++c_) {
    int i_ = c_ * 256 + tid, row_ = i_ >> 3, ch_ = i_ & 7;
    int f_ = (row_ & 3) | ((((row_ >> 3) ^ (row_ >> 4)) & 1) << 2);
    kS[c_] = Kb + row_ * 64 + (ch_ ^ f_) * 8;
    kD[c_] = i_ * 8;
  }
  const u16* vS[4]; int vD[4];
  #pragma unroll
  for (int c_ = 0; c_ < 4; ++c_) {
    int i_ = c_ * 256 + tid, row_ = i_ >> 4, ch_ = i_ & 15;
    vS[c_] = Vb + row_ * 1024 + (ch_ ^ (row_ & 15)) * 8;
    vD[c_] = i_ * 8;
  }

#define STAGE_K(bi, t) do { _Pragma("unroll")                                                 \
    for (int c_ = 0; c_ < 4; ++c_)                                                           \
      __builtin_amdgcn_global_load_lds(                                                      \
        (const __attribute__((address_space(1))) void*)(kS[c_] + (t) * 8192),                \
        (__attribute__((address_space(3))) void*)&KVl[bi][kD[c_]], 16, 0, 0); } while (0)

#define STAGE_V(bi, t) do { _Pragma("unroll")                                                 \
    for (int c_ = 0; c_ < 4; ++c_)                                                           \
      __builtin_amdgcn_global_load_lds(                                                      \
        (const __attribute__((address_space(1))) void*)(vS[c_] + (t) * 128),                 \
        (__attribute__((address_space(3))) void*)&KVl[bi][vD[c_]], 16, 0, 0); } while (0)

  STAGE_K(0, 0);

  for (int i = tid; i < 1024; i += 256) maskL2[i] = mask[b * 1024 + i] * L2E;

  // Q fragments: 32 rows (qg 0,1)
  bf16x8 qf[2][2];
  #pragma unroll
  for (int qg = 0; qg < 2; ++qg) {
    const u16* Qp = Q + ((size_t)bh * 1024 + qb + qg * 16 + lq) * 64 + g * 8;
    qf[qg][0] = *(const bf16x8*)Qp;
    qf[qg][1] = *(const bf16x8*)(Qp + 32);
  }

  // ---- hoisted LDS read offsets (lane-constant) ----
  int kOff[2][2];
  #pragma unroll
  for (int c = 0; c < 2; ++c) {
    int row128 = w * 32 + ((lq >> 2) << 3) + c * 4 + (lq & 3);   // kappa(A-row = lq)
    int F = (row128 & 3) | ((((row128 >> 3) ^ (row128 >> 4)) & 1) << 2);
    kOff[c][0] = row128 * 64 + ((g ^ F) * 8);
    kOff[c][1] = row128 * 64 + (((g + 4) ^ F) * 8);
  }
  int vOff[4];
  #pragma unroll
  for (int dc = 0; dc < 4; ++dc) {
    int row = dc * 16 + lq;
    vOff[dc] = row * 128 + (((w * 4 + g) ^ (row & 15)) * 8);
  }
  int mBase = w * 32 + g * 8;   // mask index = t*128 + mBase + c*4

  __syncthreads();   // K0 staged + maskL2 ready

  // ---- pass A: swapped QK^T (quarter x 32q), E = exp2(s+mkl) packed to sp[64], Z1 ----
  const float sl2e = 0.125f * L2E;
  unsigned sp[64];
  float z1[2] = {0.f, 0.f};
  int cur = 0;
  #pragma unroll
  for (int t = 0; t < 8; ++t) {
    if (t < 7) STAGE_K(cur ^ 1, t + 1);
    else       STAGE_V(0, 0);            // prefetch pass-B V tile 0 (KVl[0] dead: cur==1 at t=7)
    #pragma unroll
    for (int c = 0; c < 2; ++c) {
      bf16x8 kf0 = *(const bf16x8*)&KVl[cur][kOff[c][0]];
      bf16x8 kf1 = *(const bf16x8*)&KVl[cur][kOff[c][1]];
      const float4 mk = *(const float4*)&maskL2[t * 128 + mBase + c * 4];
      #pragma unroll
      for (int qg = 0; qg < 2; ++qg) {
        f32x4 tt = {0.f, 0.f, 0.f, 0.f};
        tt = __builtin_amdgcn_mfma_f32_16x16x32_bf16(kf0, qf[qg][0], tt, 0, 0, 0);
        tt = __builtin_amdgcn_mfma_f32_16x16x32_bf16(kf1, qf[qg][1], tt, 0, 0, 0);
        float e0 = __builtin_amdgcn_exp2f(fmaf(tt[0], sl2e, mk.x));
        float e1 = __builtin_amdgcn_exp2f(fmaf(tt[1], sl2e, mk.y));
        float e2 = __builtin_amdgcn_exp2f(fmaf(tt[2], sl2e, mk.z));
        float e3 = __builtin_amdgcn_exp2f(fmaf(tt[3], sl2e, mk.w));
        z1[qg] += (e0 + e1) + (e2 + e3);
        sp[t * 8 + qg * 4 + c * 2 + 0] = cvtpk(e0, e1);
        sp[t * 8 + qg * 4 + c * 2 + 1] = cvtpk(e2, e3);
      }
    }
    __syncthreads();
    cur ^= 1;
  }

  // ---- merge Z1: g-groups (shfl) + 4 waves (LDS) -> cr[qg] = L2E / Z1 ----
  #pragma unroll
  for (int qg = 0; qg < 2; ++qg) {
    z1[qg] += __shfl_xor(z1[qg], 16);
    z1[qg] += __shfl_xor(z1[qg], 32);
  }
  if (l < 16) { z1p[w][l] = z1[0]; z1p[w][16 + l] = z1[1]; }
  __syncthreads();
  float cr[2];
  #pragma unroll
  for (int qg = 0; qg < 2; ++qg) {
    int q = qg * 16 + lq;
    float Z1 = (z1p[0][q] + z1p[1][q]) + (z1p[2][q] + z1p[3][q]);
    cr[qg] = L2E * __builtin_amdgcn_rcpf(Z1);
  }

  // ---- pass B: p2 = exp2(mkl - cr*E), PV over V dbuf (tile t in KVl[t&1]) ----
  f32x4 acc[2][4] = {};
  float z2[2] = {0.f, 0.f};
  #pragma unroll
  for (int t = 0; t < 8; ++t) {
    if (t < 7) STAGE_V((t + 1) & 1, t + 1);
    u32x4 pk[2];
    #pragma unroll
    for (int qg = 0; qg < 2; ++qg) {
      if (cl) {
        #pragma unroll
        for (int j = 0; j < 4; ++j) {
          unsigned e = sp[t * 8 + qg * 4 + j];
          float mkA = maskL2[t * 128 + mBase + 2 * j];
          float mkB = maskL2[t * 128 + mBase + 2 * j + 1];
          float pA = __builtin_amdgcn_exp2f(fmaf(-cr[qg], lo16(e), mkA));
          float pB = __builtin_amdgcn_exp2f(fmaf(-cr[qg], hi16(e), mkB));
          z2[qg] += pA + pB;
          pk[qg][j] = cvtpk(pA, pB);
        }
      } else {
        pk[qg] = *(u32x4*)&sp[t * 8 + qg * 4];   // unnormalized E; epilogue scales by 1/Z1
      }
    }
    #pragma unroll
    for (int dc = 0; dc < 4; ++dc) {
      bf16x8 vf = *(const bf16x8*)&KVl[t & 1][vOff[dc]];
      #pragma unroll
      for (int qg = 0; qg < 2; ++qg)
        acc[qg][dc] = __builtin_amdgcn_mfma_f32_16x16x32_bf16(
            __builtin_bit_cast(bf16x8, pk[qg]), vf, acc[qg][dc], 0, 0, 0);
    }
    if (t < 7) __syncthreads();            // tile t reads done + tile t+1 staged/visible
  }

  // ---- epilogue: 4-way Z2 merge + 4-way acc reduction through dead KVl ----
  #pragma unroll
  for (int qg = 0; qg < 2; ++qg) {
    z2[qg] += __shfl_xor(z2[qg], 16);
    z2[qg] += __shfl_xor(z2[qg], 32);
  }
  if (l < 16) { z2p[w][l] = z2[0]; z2p[w][16 + l] = z2[1]; }
  float* redF = (float*)&KVl[0][0];    // [3][32 q][68 d-stride] = 26112 B, KVl[0] dead since t=6 barrier
  if (w > 0) {
    #pragma unroll
    for (int qg = 0; qg < 2; ++qg)
      #pragma unroll
      for (int dc = 0; dc < 4; ++dc)
        #pragma unroll
        for (int r = 0; r < 4; ++r)
          redF[(w - 1) * 2176 + (qg * 16 + g * 4 + r) * 68 + dc * 16 + lq] = acc[qg][dc][r];
  }
  __syncthreads();
  if (w == 0) {
    #pragma unroll
    for (int qg = 0; qg < 2; ++qg) {
      #pragma unroll
      for (int r = 0; r < 4; ++r) {
        int q = qg * 16 + g * 4 + r;
        float phi;
        if (cl) {
          float Z2 = (z2p[0][q] + z2p[1][q]) + (z2p[2][q] + z2p[3][q]);
          phi = __builtin_amdgcn_rcpf(Z2);
        } else {
          float Z1 = (z1p[0][q] + z1p[1][q]) + (z1p[2][q] + z1p[3][q]);
          phi = __builtin_amdgcn_rcpf(Z1);
        }
        size_t orow = ((size_t)(b * 1024 + qb + q)) * 1024 + h * 64;
        #pragma unroll
        for (int dc = 0; dc < 4; ++dc) {
          int dq = q * 68 + dc * 16 + lq;
          float o = acc[qg][dc][r] + redF[dq] + redF[2176 + dq] + redF[4352 + dq];
          out[orow + dc * 16 + lq] = o * phi;
        }
      }
    }
  }
#undef STAGE_K
#undef STAGE_V
}

extern "C" void kernel_launch(void* const* d_in, const int* in_sizes, int n_in,
                              void* d_out, int out_size, void* d_ws, size_t ws_size,
                              hipStream_t stream) {
  const float* s1   = (const float*)d_in[0];
  const float* s2   = (const float*)d_in[1];
  const float* mask = (const float*)d_in[2];
  const float* Wq   = (const float*)d_in[3];
  const float* bq   = (const float*)d_in[4];
  const float* Wk   = (const float*)d_in[5];
  const float* bk   = (const float*)d_in[6];
  const float* Wv   = (const float*)d_in[7];
  const float* bv   = (const float*)d_in[8];
  const int*   cl   = (const int*)d_in[9];
  float* out = (float*)d_out;

  // ws layout (u16 elements): X1[8M] X2[8M] Wtq[1M] Wtk[1M] Wtv[1M] Q[8M] K[8M] Vt[8M]
  u16* ws  = (u16*)d_ws;
  const size_t M1 = 1024 * 1024;
  u16* X1  = ws;                 // X2 = X1 + 8M (contiguous -> fused conv writes linearly)
  u16* Wtq = ws + 16 * M1;
  u16* Wtk = Wtq + M1;
  u16* Wtv = Wtk + M1;
  u16* Qb  = Wtv + M1;
  u16* Kb  = Qb + 8 * M1;
  u16* Vtb = Kb + 8 * M1;        // V^T written directly by qkv_gemm3 (z==2)
  u16* X2  = ws + 8 * M1;

  conv2_f32_bf16<<<2048, 256, 0, stream>>>(s1, s2, X1, 2097152, 4194304);
  wtrans3<<<dim3(32, 32, 3), dim3(32, 8), 0, stream>>>(Wq, Wk, Wv, Wtq, Wtk, Wtv);
  qkv_gemm3<<<1536, 256, 0, stream>>>(X1, X2, Wtq, Wtk, Wtv, bq, bk, bv, Qb, Kb, Vtb);
  attn13<<<4096, 256, 0, stream>>>(Qb, Kb, Vtb, mask, cl, out);
}